// Round 10
// baseline (541.511 us; speedup 1.0000x reference)
//
#include <hip/hip_runtime.h>
#include <math.h>

#define BB 32
#define SS 65536
#define CC 20
#define NM 16
#define HH 128
#define SP 256   // DFT LDS row pitch (bf16 elems), XOR-chunk swizzled (R21)
#define WP 64    // hT row pitch (bf16 elems): 8x short8 payload, XOR-swizzled chunks
#define NSLOT 16

using short8  = __attribute__((ext_vector_type(8))) short;
using floatx4 = __attribute__((ext_vector_type(4))) float;
using floatx2 = __attribute__((ext_vector_type(2))) float;

__device__ __forceinline__ unsigned short f2bf(float f) {
    union { float f; unsigned u; } v; v.f = f;
    unsigned u = v.u;
    return (unsigned short)((u + 0x7FFFu + ((u >> 16) & 1u)) >> 16);   // RNE
}
__device__ __forceinline__ float bf2f(unsigned short h) {
    union { unsigned u; float f; } v; v.u = ((unsigned)h) << 16; return v.f;
}
__device__ __forceinline__ unsigned short f2bflo(float a) {
    return f2bf(a - bf2f(f2bf(a)));
}
__device__ __forceinline__ unsigned pk2(unsigned short lo, unsigned short hi) {
    return (unsigned)lo | ((unsigned)hi << 16);
}
__device__ __forceinline__ float asf(unsigned u) {
    union { unsigned u; float f; } v; v.u = u; return v.f;
}
// R23: hardware packed f32->bf16 RNE — 1 VALU op replaces 2x 4-op software RNE.
__device__ __forceinline__ unsigned cvtpk(float lo, float hi) {
    unsigned r;
    asm("v_cvt_pk_bf16_f32 %0, %1, %2" : "=v"(r) : "v"(lo), "v"(hi));
    return r;
}

// Tanh-form gelu, native exp2/rcp (R11). |delta| vs erf-gelu ~3e-4.
__device__ __forceinline__ float gelu_fast(float v) {
    float u = v * v;
    float inner = v * fmaf(0.0356774081f, u, 0.7978845608f);
    float e = __builtin_amdgcn_exp2f(inner * 2.8853900818f);
    float r = __builtin_amdgcn_rcpf(e + 1.0f);
    return fmaf(-v, r, v);
}

// R24: paired gelu on float2 — polynomial part vectorizes to v_pk_mul/v_pk_fma
// (VOP3P, CDNA2+); exp2/rcp stay scalar (no packed trans). ~2x fewer VALU ops
// on the f32 arithmetic vs two scalar gelu_fast calls.
__device__ __forceinline__ floatx2 gelu2(floatx2 v) {
    floatx2 u = v * v;
    floatx2 inner = v * (u * 0.0356774081f + 0.7978845608f);
    floatx2 z = inner * 2.8853900818f;
    floatx2 e, r;
    e.x = __builtin_amdgcn_exp2f(z.x);
    e.y = __builtin_amdgcn_exp2f(z.y);
    r.x = __builtin_amdgcn_rcpf(e.x + 1.0f);
    r.y = __builtin_amdgcn_rcpf(e.y + 1.0f);
    return v - v * r;
}

// R20: exact 16-lane (DPP-row) sum via rotation reduce. row_ror:n = 0x120|n.
__device__ __forceinline__ float row16_sum(float p) {
    union { float f; int i; } v, w;
    v.f = p;
    w.i = __builtin_amdgcn_update_dpp(0, v.i, 0x121, 0xF, 0xF, true); v.f += w.f;
    w.i = __builtin_amdgcn_update_dpp(0, v.i, 0x122, 0xF, 0xF, true); v.f += w.f;
    w.i = __builtin_amdgcn_update_dpp(0, v.i, 0x124, 0xF, 0xF, true); v.f += w.f;
    w.i = __builtin_amdgcn_update_dpp(0, v.i, 0x128, 0xF, 0xF, true); v.f += w.f;
    return v.f;
}

// R21: swizzled sh_* addressing — row pitch 256 ushort (512B, pow2), 16B-chunk
// XOR on row&7. Bank cost of dft_phase b128 reads: 2-way max (free, m136).
__device__ __forceinline__ int swzi(int row, int scol) {   // ushort index
    return row * SP + ((((scol >> 3) ^ row) & 7) << 3) + (scol & 7);
}

// R19/R20: shared A-row staging — [h(20)|1|pad(11)|cm_hi(16)|sm_hi(16)],
// XOR-chunk swizzled. Chunks 4..7 come straight from the trig table row.
__device__ __forceinline__ void stage_A(unsigned short* AST, int tid,
                                        const unsigned* hw,
                                        uint4 tc0, uint4 tc1, uint4 ts0, uint4 ts1) {
    int sw = tid & 7;
    unsigned* base = (unsigned*)(AST + tid * 64);
    *(uint4*)(base + ((0 ^ sw) << 2)) = (uint4){hw[0], hw[1], hw[2], hw[3]};
    *(uint4*)(base + ((1 ^ sw) << 2)) = (uint4){hw[4], hw[5], hw[6], hw[7]};
    *(uint4*)(base + ((2 ^ sw) << 2)) = (uint4){hw[8], hw[9], 0x00003F80u, 0u};  // h16..19, ONE, 0
    *(uint4*)(base + ((3 ^ sw) << 2)) = (uint4){0u, 0u, 0u, 0u};
    *(uint4*)(base + ((4 ^ sw) << 2)) = tc0;
    *(uint4*)(base + ((5 ^ sw) << 2)) = tc1;
    *(uint4*)(base + ((6 ^ sw) << 2)) = ts0;
    *(uint4*)(base + ((7 ^ sw) << 2)) = ts1;
}

// ---------------- k_prep: max-reduce + zero cP + w1T + trig table ----------
__global__ __launch_bounds__(256) void k_prep(const float* __restrict__ pd,
                                              const float* __restrict__ w1,
                                              const float* __restrict__ b1f,
                                              float* __restrict__ invmax,
                                              float* __restrict__ cP,
                                              unsigned short* __restrict__ w1Tg,
                                              unsigned* __restrict__ trigT) {
    int bx = blockIdx.x;
    if (bx == 0) {
        __shared__ float red[256];
        int t = threadIdx.x;
        float m = -1e30f;
        for (int i = t; i < SS; i += 256) m = fmaxf(m, pd[i]);
        red[t] = m; __syncthreads();
        for (int off = 128; off > 0; off >>= 1) {
            if (t < off) red[t] = fmaxf(red[t], red[t + off]);
            __syncthreads();
        }
        if (t == 0) invmax[0] = 1.0f / red[0];
    } else if (bx <= 1280) {
        int idx = (bx - 1) * 256 + threadIdx.x;   // 1280*256 float4 = 4*16*32*640 floats
        float4 z = {0.f, 0.f, 0.f, 0.f};
        ((float4*)cP)[idx] = z;
    } else if (bx == 1281) {
        for (int idx = threadIdx.x; idx < HH * 64; idx += 256) {
            int j = idx >> 6, k = idx & 63;
            unsigned short r = 0;
            if (k < CC) r = f2bf(w1[k * HH + j]);
            else if (k == CC) r = f2bf(b1f[j]);
            else if (k >= 32 && k < 32 + CC) r = f2bflo(w1[(k - 32) * HH + j]);
            else if (k == 32 + CC) r = f2bflo(b1f[j]);
            w1Tg[idx] = r;
        }
    } else {   // bx in [1282, 1537]: trig table
        int s = (bx - 1282) * 256 + threadIdx.x;
        float u = (float)s * (1.0f / 32768.0f);
        float s1, c1; sincospif(u, &s1, &c1);
        float cm = 1.0f, sm = 0.0f;
        unsigned short ch[NM], sh[NM];
        #pragma unroll
        for (int m = 0; m < NM; ++m) {
            ch[m] = f2bf(cm); sh[m] = f2bf(sm);
            float cn = cm * c1 - sm * s1;
            sm = sm * c1 + cm * s1;
            cm = cn;
        }
        uint4* row = (uint4*)(trigT + (size_t)s * 16);
        row[0] = (uint4){pk2(ch[0],ch[1]), pk2(ch[2],ch[3]), pk2(ch[4],ch[5]), pk2(ch[6],ch[7])};
        row[1] = (uint4){pk2(ch[8],ch[9]), pk2(ch[10],ch[11]), pk2(ch[12],ch[13]), pk2(ch[14],ch[15])};
        row[2] = (uint4){pk2(sh[0],sh[1]), pk2(sh[2],sh[3]), pk2(sh[4],sh[5]), pk2(sh[6],sh[7])};
        row[3] = (uint4){pk2(sh[8],sh[9]), pk2(sh[10],sh[11]), pk2(sh[12],sh[13]), pk2(sh[14],sh[15])};
    }
}

// ---------------- shared DFT tail: LDS-staged MFMA partial DFT --------------
// R21: swizzled pitch-256 reads; (16+frow)&7 == frow&7 so one swizzle value.
__device__ __forceinline__ void dft_phase(unsigned short* sh_hA, unsigned short* sh_ph,
                                          int tid, float* cPdst) {
    int wave = tid >> 6, lane = tid & 63;
    int quad = lane >> 4, frow = lane & 15;
    floatx4 acc00 = {0.f,0.f,0.f,0.f}, acc01 = {0.f,0.f,0.f,0.f};
    floatx4 acc10 = {0.f,0.f,0.f,0.f}, acc11 = {0.f,0.f,0.f,0.f};
    int kb = wave * 64 + quad * 8;
    #pragma unroll
    for (int kc = 0; kc < 2; ++kc) {
        int k = kb + kc * 32;
        int co = (((k >> 3) ^ frow) & 7) << 3;     // swizzled chunk offset
        short8 a0 = *(const short8*)(sh_hA + frow * SP + co);
        short8 a1 = *(const short8*)(sh_hA + (16 + frow) * SP + co);
        short8 bc = *(const short8*)(sh_ph + frow * SP + co);
        short8 bs = *(const short8*)(sh_ph + (16 + frow) * SP + co);
        acc00 = __builtin_amdgcn_mfma_f32_16x16x32_bf16(a0, bc, acc00, 0, 0, 0);
        acc01 = __builtin_amdgcn_mfma_f32_16x16x32_bf16(a0, bs, acc01, 0, 0, 0);
        acc10 = __builtin_amdgcn_mfma_f32_16x16x32_bf16(a1, bc, acc10, 0, 0, 0);
        acc11 = __builtin_amdgcn_mfma_f32_16x16x32_bf16(a1, bs, acc11, 0, 0, 0);
    }
    __syncthreads();
    float* red = (float*)sh_hA;
    #pragma unroll
    for (int r = 0; r < 4; ++r) {
        red[wave * 1024 + 0 * 256 + r * 64 + lane] = acc00[r];
        red[wave * 1024 + 1 * 256 + r * 64 + lane] = acc01[r];
        red[wave * 1024 + 2 * 256 + r * 64 + lane] = acc10[r];
        red[wave * 1024 + 3 * 256 + r * 64 + lane] = acc11[r];
    }
    __syncthreads();
    #pragma unroll
    for (int ii = 0; ii < 4; ++ii) {
        int idx = ii * 256 + tid;
        float v = red[idx] + red[1024 + idx] + red[2048 + idx] + red[3072 + idx];
        int f = idx >> 8;
        int r = (idx >> 6) & 3, ln = idx & 63;
        int o = (f >> 1) * 16 + (ln >> 4) * 4 + r;   // D row = quad*4+reg
        int m = ln & 15;                              // D col = lane&15
        if (o < CC) atomicAdd(cPdst + (f & 1) * 320 + o * 16 + m, v);
    }
}

// ---------------- k_fc0_dft: h2 (paired bf16 dwords) = fc0; DFT partials ----
// R22 bounds (256,4); R23 cvt_pk; R24 packed-f32 affine math.
__global__ __launch_bounds__(256, 4) void k_fc0_dft(const float* __restrict__ x,
        const float* __restrict__ pd, const float* __restrict__ w,
        const float* __restrict__ bias, const float* __restrict__ invmax,
        const unsigned* __restrict__ trigT,
        unsigned* __restrict__ h2, float* __restrict__ cP0) {
    __shared__ __align__(16) unsigned short LB[2 * 32 * SP];   // 32768 B exactly
    unsigned short* sh_hA = LB;
    unsigned short* sh_ph = LB + 32 * SP;
    int tid = threadIdx.x;
    {
        unsigned* z = (unsigned*)(sh_hA + CC * SP);
        for (int i = tid; i < (32 - CC) * SP / 2; i += 256) z[i] = 0;
    }
    int b = blockIdx.y;
    int s = blockIdx.x * 256 + tid;
    float xv = x[(size_t)b * SS + s];
    float g  = pd[s] * invmax[0];
    unsigned* hp2 = h2 + (size_t)b * (CC / 2) * SS + s;
    const uint4* trow = (const uint4*)(trigT + (size_t)s * 16);
    uint4 tc0 = trow[0], tc1 = trow[1], ts0 = trow[2], ts1 = trow[3];
    unsigned c8[8] = {tc0.x, tc0.y, tc0.z, tc0.w, tc1.x, tc1.y, tc1.z, tc1.w};
    unsigned s8[8] = {ts0.x, ts0.y, ts0.z, ts0.w, ts1.x, ts1.y, ts1.z, ts1.w};
    #pragma unroll
    for (int m = 0; m < NM; ++m) {
        unsigned cd = c8[m >> 1], sd = s8[m >> 1];
        sh_ph[swzi(m, tid)]      = (unsigned short)((m & 1) ? (cd >> 16) : (cd & 0xFFFFu));
        sh_ph[swzi(16 + m, tid)] = (unsigned short)((m & 1) ? (sd >> 16) : (sd & 0xFFFFu));
    }
    #pragma unroll
    for (int p = 0; p < CC / 2; ++p) {
        int c0 = 2 * p, c1i = 2 * p + 1;
        // R24: packed affine (scalar s_loads stay scalar — R15 lesson)
        floatx2 wv = {w[c0], w[c1i]};
        floatx2 gv = {w[CC + c0], w[CC + c1i]};
        floatx2 bv = {bias[c0], bias[c1i]};
        floatx2 v = wv * xv + gv * g + bv;
        unsigned dw = cvtpk(v.x, v.y);                 // R23: HW RNE pair
        hp2[(size_t)p * SS] = dw;
        sh_hA[swzi(c0, tid)]  = (unsigned short)(dw & 0xFFFFu);
        sh_hA[swzi(c1i, tid)] = (unsigned short)(dw >> 16);
    }
    __syncthreads();
    dft_phase(sh_hA, sh_ph, tid, cP0 + ((size_t)(blockIdx.x & (NSLOT - 1)) * BB + b) * 640);
}

// ---------------- k_point_dft (layers 0..2): MFMA point-op + next-layer DFT -
// R19 structure + R20 trig table + R21 swizzle + R22 bounds + R23 cvt_pk;
// R24: packed-f32 gelu2.
__global__ __launch_bounds__(256, 4) void k_point_dft(unsigned* __restrict__ h2,
        const unsigned short* __restrict__ Bpk,
        const unsigned* __restrict__ trigT,
        float* __restrict__ cPn) {
    __shared__ __align__(16) unsigned short LB[2 * 32 * SP];   // 32768 B exactly
    unsigned short* AST   = LB;                  // 32 KB staged A-rows (all of LB)
    unsigned short* sh_hA = LB;                  // aliases, valid after barrier
    unsigned short* sh_ph = LB + 32 * SP;
    int tid = threadIdx.x;
    int b = blockIdx.y;
    int s = blockIdx.x * 256 + tid;

    // ---- phase A: table load + old-h load + A-row staging (wave-local) ----
    const uint4* trow = (const uint4*)(trigT + (size_t)s * 16);
    uint4 tc0 = trow[0], tc1 = trow[1], ts0 = trow[2], ts1 = trow[3];
    const unsigned* hp2r = h2 + (size_t)b * (CC / 2) * SS + s;
    unsigned hw[CC / 2];
    #pragma unroll
    for (int p = 0; p < CC / 2; ++p) hw[p] = hp2r[(size_t)p * SS];
    stage_A(AST, tid, hw, tc0, tc1, ts0, ts1);
    // no barrier: phase B reads only this wave's rows, written by this wave

    // ---- phase B: MFMA point-op (swapped), gelu, in-lane pack, h2 -----
    int wave = tid >> 6, lane = tid & 63, col = lane & 15, quad = lane >> 4;
    const unsigned short* Bp = Bpk + (size_t)b * 4096;
    short8 wh0[2], wh1[2], wl0[2], wl1[2];
    #pragma unroll
    for (int cht = 0; cht < 2; ++cht) {
        int o = cht * 16 + col;
        wh0[cht] = *(const short8*)(Bp + o * 64 + quad * 8);
        wh1[cht] = *(const short8*)(Bp + o * 64 + 32 + quad * 8);
        wl0[cht] = *(const short8*)(Bp + 2048 + o * 64 + quad * 8);
        wl1[cht] = *(const short8*)(Bp + 2048 + o * 64 + 32 + quad * 8);
    }
    unsigned* h2b = h2 + (size_t)b * (CC / 2) * SS + blockIdx.x * 256;
    unsigned pkr[2][4][2];
    #pragma unroll
    for (int st = 0; st < 4; ++st) {
        int ar = wave * 64 + st * 16 + col;
        int sw = ar & 7;
        const unsigned short* abase = AST + ar * 64;
        short8 ah0 = *(const short8*)(abase + ((quad ^ sw) << 3));
        short8 ah1 = *(const short8*)(abase + (((4 + quad) ^ sw) << 3));
        #pragma unroll
        for (int cht = 0; cht < 2; ++cht) {
            floatx4 a = {0.f, 0.f, 0.f, 0.f};
            a = __builtin_amdgcn_mfma_f32_16x16x32_bf16(wh0[cht], ah0, a, 0, 0, 0);
            a = __builtin_amdgcn_mfma_f32_16x16x32_bf16(wh1[cht], ah1, a, 0, 0, 0);
            a = __builtin_amdgcn_mfma_f32_16x16x32_bf16(wl0[cht], ah0, a, 0, 0, 0);
            a = __builtin_amdgcn_mfma_f32_16x16x32_bf16(wl1[cht], ah1, a, 0, 0, 0);
            floatx2 g01 = gelu2((floatx2){a[0], a[1]});   // R24
            floatx2 g23 = gelu2((floatx2){a[2], a[3]});
            unsigned d0 = cvtpk(g01.x, g01.y);
            unsigned d1 = cvtpk(g23.x, g23.y);
            pkr[cht][st][0] = d0;
            pkr[cht][st][1] = d1;
            int p = cht * 8 + quad * 2;               // channel pair index
            if (p < CC / 2) {                          // cht1: quad0 only
                h2b[(size_t)p * SS + ar]       = d0;
                h2b[(size_t)(p + 1) * SS + ar] = d1;
            }
        }
    }
    __syncthreads();   // all waves' AST reads done; LDS becomes sh_hA/sh_ph

    // ---- phase C: scatter h_new to sh_hA, write sh_ph from table ------
    {
        unsigned* z = (unsigned*)(sh_hA + CC * SP);
        #pragma unroll
        for (int i = tid; i < (32 - CC) * SP / 2; i += 256) z[i] = 0;
    }
    {
        unsigned c8[8] = {tc0.x, tc0.y, tc0.z, tc0.w, tc1.x, tc1.y, tc1.z, tc1.w};
        unsigned s8[8] = {ts0.x, ts0.y, ts0.z, ts0.w, ts1.x, ts1.y, ts1.z, ts1.w};
        #pragma unroll
        for (int m = 0; m < NM; ++m) {
            unsigned cd = c8[m >> 1], sd = s8[m >> 1];
            sh_ph[swzi(m, tid)]      = (unsigned short)((m & 1) ? (cd >> 16) : (cd & 0xFFFFu));
            sh_ph[swzi(16 + m, tid)] = (unsigned short)((m & 1) ? (sd >> 16) : (sd & 0xFFFFu));
        }
    }
    #pragma unroll
    for (int cht = 0; cht < 2; ++cht) {
        int ob = cht * 16 + quad * 4;
        if (ob < CC) {
            #pragma unroll
            for (int st = 0; st < 4; ++st) {
                int s_loc = wave * 64 + st * 16 + col;
                #pragma unroll
                for (int rp = 0; rp < 2; ++rp) {
                    unsigned d = pkr[cht][st][rp];
                    sh_hA[swzi(ob + 2 * rp, s_loc)]     = (unsigned short)(d & 0xFFFFu);
                    sh_hA[swzi(ob + 2 * rp + 1, s_loc)] = (unsigned short)(d >> 16);
                }
            }
        }
    }
    __syncthreads();
    dft_phase(sh_hA, sh_ph, tid, cPn + ((size_t)(blockIdx.x & (NSLOT - 1)) * BB + b) * 640);
}

// ---------------- k_mix: partial reduce + complex mixing + B-panel pack -----
__global__ __launch_bounds__(320) void k_mix(const float* __restrict__ cP,
                                             const float* __restrict__ wre, const float* __restrict__ wim,
                                             const float* __restrict__ ww, const float* __restrict__ wb,
                                             float* __restrict__ cA, float* __restrict__ cB,
                                             unsigned short* __restrict__ Bpk) {
    int b = blockIdx.x, tid = threadIdx.x;
    __shared__ float PQ[640];
    const float* base = cP + (size_t)b * 640;
    int i = tid >> 4, m = tid & 15;
    float sP = 0.f, sQ = 0.f;
    #pragma unroll 4
    for (int sl = 0; sl < NSLOT; ++sl) {
        sP += base[(size_t)sl * BB * 640 + tid];
        sQ += base[(size_t)sl * BB * 640 + 320 + tid];
    }
    PQ[i * 32 + m]      = sP;
    PQ[i * 32 + 16 + m] = sQ;
    __syncthreads();
    int o = i;
    float reY = 0.f, imY = 0.f;
    #pragma unroll
    for (int c = 0; c < CC; ++c) {
        float P = PQ[c * 32 + m], Q = PQ[c * 32 + 16 + m];
        float wr = wre[(size_t)(c * CC + o) * NM + m];
        float wi = wim[(size_t)(c * CC + o) * NM + m];
        reY += P * wr + Q * wi;                // X = P - iQ
        imY += P * wi - Q * wr;
    }
    const float invS = 1.0f / (float)SS;
    float a, bb;
    if (m == 0) { a = reY * invS; bb = 0.0f; } // irfft drops Im(DC)
    else        { a = 2.0f * reY * invS; bb = -2.0f * imY * invS; }
    cA[(size_t)(b * CC + o) * NM + m] = a;
    cB[(size_t)(b * CC + o) * NM + m] = bb;

    // ---- pack B panels for the MFMA point-op (per-b) ------------------
    unsigned short* Bp = Bpk + (size_t)b * 4096;
    for (int idx = tid; idx < 640; idx += 320) {       // o<20, k 0..31
        int o8 = idx >> 5, k = idx & 31;
        float v = 0.f;
        if (k < CC) v = ww[o8 * CC + k];
        else if (k == CC) v = wb[o8];
        Bp[o8 * 64 + k]        = f2bf(v);
        Bp[2048 + o8 * 64 + k] = f2bflo(v);
    }
    for (int idx = tid; idx < 768; idx += 320) {       // o 20..31: zero rows
        int o8 = 20 + (idx >> 6), k = idx & 63;
        Bp[o8 * 64 + k] = 0;
        Bp[2048 + o8 * 64 + k] = 0;
    }
    Bp[o * 64 + 32 + m]        = f2bf(a);
    Bp[o * 64 + 48 + m]        = f2bf(bb);
    Bp[2048 + o * 64 + 32 + m] = f2bflo(a);
    Bp[2048 + o * 64 + 48 + m] = f2bflo(bb);
}

// ---------------- k_point_final: MFMA layer-3 point op + fc1 + gelu + fc2 ---
// R22 geometry (128 threads, hT 16 KB); R23 cvt_pk; R24 packed gelu2 + pk subs.
__global__ __launch_bounds__(128, 4) void k_point_final(const unsigned* __restrict__ h2,
        const unsigned short* __restrict__ Bpk,
        const unsigned short* __restrict__ w1Tg,
        const float* __restrict__ w2, const float* __restrict__ b2,
        const unsigned* __restrict__ trigT,
        float* __restrict__ out) {
    __shared__ __align__(16) unsigned short AST[128 * 64];   // 16384 B
    unsigned short* hT = AST;            // aliased, wave-local throughout
    int tid = threadIdx.x;
    int b = blockIdx.y;
    int s = blockIdx.x * 128 + tid;

    // ---- phase A: table load + h load + A-row staging -----------------
    const uint4* trow = (const uint4*)(trigT + (size_t)s * 16);
    uint4 tc0 = trow[0], tc1 = trow[1], ts0 = trow[2], ts1 = trow[3];
    const unsigned* hp2r = h2 + (size_t)b * (CC / 2) * SS + s;
    unsigned hw[CC / 2];
    #pragma unroll
    for (int p = 0; p < CC / 2; ++p) hw[p] = hp2r[(size_t)p * SS];
    stage_A(AST, tid, hw, tc0, tc1, ts0, ts1);
    // no barrier: wave-local

    // ---- phase B: point-op MFMA (swapped, no gelu) --------------------
    int wave = tid >> 6, lane = tid & 63, col = lane & 15, quad = lane >> 4;
    const unsigned short* Bp = Bpk + (size_t)b * 4096;
    short8 wh0[2], wh1[2], wl0[2], wl1[2];
    #pragma unroll
    for (int cht = 0; cht < 2; ++cht) {
        int o = cht * 16 + col;
        wh0[cht] = *(const short8*)(Bp + o * 64 + quad * 8);
        wh1[cht] = *(const short8*)(Bp + o * 64 + 32 + quad * 8);
        wl0[cht] = *(const short8*)(Bp + 2048 + o * 64 + quad * 8);
        wl1[cht] = *(const short8*)(Bp + 2048 + o * 64 + 32 + quad * 8);
    }
    float res[2][4][4];   // [cht][st][r] — statically indexed
    #pragma unroll
    for (int st = 0; st < 4; ++st) {
        int ar = wave * 64 + st * 16 + col;
        int sw = ar & 7;
        const unsigned short* abase = AST + ar * 64;
        short8 ah0 = *(const short8*)(abase + ((quad ^ sw) << 3));
        short8 ah1 = *(const short8*)(abase + (((4 + quad) ^ sw) << 3));
        #pragma unroll
        for (int cht = 0; cht < 2; ++cht) {
            floatx4 a = {0.f, 0.f, 0.f, 0.f};
            a = __builtin_amdgcn_mfma_f32_16x16x32_bf16(wh0[cht], ah0, a, 0, 0, 0);
            a = __builtin_amdgcn_mfma_f32_16x16x32_bf16(wh1[cht], ah1, a, 0, 0, 0);
            a = __builtin_amdgcn_mfma_f32_16x16x32_bf16(wl0[cht], ah0, a, 0, 0, 0);
            a = __builtin_amdgcn_mfma_f32_16x16x32_bf16(wl1[cht], ah1, a, 0, 0, 0);
            #pragma unroll
            for (int r = 0; r < 4; ++r) res[cht][st][r] = a[r];
        }
    }
    // no barrier: phase C writes this wave's own rows only

    // ---- phase C: in-lane hi/lo cvt_pk into hT; dwi==10 = (ONE,0) slot ----
    #pragma unroll
    for (int cht = 0; cht < 2; ++cht) {
        #pragma unroll
        for (int st = 0; st < 4; ++st) {
            int row = wave * 64 + st * 16 + col;
            int sw = row & 7;
            unsigned* rb = (unsigned*)(hT + row * WP);
            #pragma unroll
            for (int rp = 0; rp < 2; ++rp) {
                int dwi = cht * 8 + quad * 2 + rp;
                if (dwi <= CC / 2) {                   // 10 = bias ONE slot
                    floatx2 f;
                    if (dwi == CC / 2) { f.x = 1.0f; f.y = 0.0f; }
                    else { f.x = res[cht][st][2 * rp]; f.y = res[cht][st][2 * rp + 1]; }
                    unsigned hd = cvtpk(f.x, f.y);                    // R23
                    floatx2 rr = {asf(hd << 16), asf(hd & 0xFFFF0000u)};
                    floatx2 d = f - rr;                               // R24: pk sub
                    unsigned ld = cvtpk(d.x, d.y);
                    int chunk = dwi >> 2, pos = dwi & 3;
                    rb[((chunk ^ sw) << 2) + pos]       = hd;
                    rb[(((chunk + 4) ^ sw) << 2) + pos] = ld;
                }
            }
        }
    }
    // no barrier: fc1 reads this wave's own rows only

    // ---- fc1 MFMA (bias in MFMA) + gelu2 + packed fc2 ------------------
    short8 bhi[8], blo[8];
    #pragma unroll
    for (int nt = 0; nt < 8; ++nt) {
        bhi[nt] = *(const short8*)(w1Tg + (size_t)(nt * 16 + col) * 64 + quad * 8);
        blo[nt] = *(const short8*)(w1Tg + (size_t)(nt * 16 + col) * 64 + 32 + quad * 8);
    }
    float w2r[8];
    #pragma unroll
    for (int nt = 0; nt < 8; ++nt) w2r[nt] = w2[nt * 16 + col];
    float b2v = b2[0];
    #pragma unroll
    for (int mt = 0; mt < 4; ++mt) {
        int srow = wave * 64 + mt * 16 + col;     // A row m = lane&15
        int sw = srow & 7;
        short8 ahi = *(const short8*)(hT + srow * WP + ((quad ^ sw) << 3));
        short8 alo = *(const short8*)(hT + srow * WP + (((quad ^ sw) ^ 4) << 3));
        floatx2 p01 = {0.f, 0.f}, p23 = {0.f, 0.f};
        #pragma unroll
        for (int nt = 0; nt < 8; ++nt) {
            floatx4 a = {0.f, 0.f, 0.f, 0.f};
            a = __builtin_amdgcn_mfma_f32_16x16x32_bf16(ahi, bhi[nt], a, 0, 0, 0);
            a = __builtin_amdgcn_mfma_f32_16x16x32_bf16(ahi, blo[nt], a, 0, 0, 0);
            a = __builtin_amdgcn_mfma_f32_16x16x32_bf16(alo, bhi[nt], a, 0, 0, 0);
            floatx2 t01 = gelu2((floatx2){a[0], a[1]});   // R24
            floatx2 t23 = gelu2((floatx2){a[2], a[3]});
            p01 += t01 * w2r[nt];                          // v_pk_fma_f32
            p23 += t23 * w2r[nt];
        }
        float pr[4] = {p01.x, p01.y, p23.x, p23.y};
        #pragma unroll
        for (int r = 0; r < 4; ++r) {
            float p = row16_sum(pr[r]);
            if (col == 0) {
                int row = wave * 64 + mt * 16 + quad * 4 + r;   // dead rows of this tile
                *(float*)(&hT[row * WP + ((row & 7) << 3)]) = p + b2v;
            }
        }
    }
    __syncthreads();      // the single cross-wave hand-off
    out[(size_t)b * SS + blockIdx.x * 128 + tid] = *(const float*)(&hT[tid * WP + ((tid & 7) << 3)]);
}

extern "C" void kernel_launch(void* const* d_in, const int* in_sizes, int n_in,
                              void* d_out, int out_size, void* d_ws, size_t ws_size,
                              hipStream_t stream) {
    (void)in_sizes; (void)n_in; (void)out_size; (void)ws_size;
    const float* x    = (const float*)d_in[0];
    const float* pd   = (const float*)d_in[1];
    const float* fc0w = (const float*)d_in[2];
    const float* fc0b = (const float*)d_in[3];
    const float* fc1w = (const float*)d_in[4];
    const float* fc1b = (const float*)d_in[5];
    const float* fc2w = (const float*)d_in[6];
    const float* fc2b = (const float*)d_in[7];

    char* ws = (char*)d_ws;
    unsigned* h2 = (unsigned*)ws;
    size_t off = (size_t)BB * (CC / 2) * SS * 4;                      // 83.9 MB (paired bf16)
    float* cP = (float*)(ws + off); off += (size_t)4 * NSLOT * BB * 640 * 4;  // 5.24 MB
    float* cA = (float*)(ws + off); off += (size_t)BB * CC * NM * 4;
    float* cB = (float*)(ws + off); off += (size_t)BB * CC * NM * 4;
    float* invmax = (float*)(ws + off); off += 256;
    unsigned short* w1Tg = (unsigned short*)(ws + off); off += (size_t)HH * 64 * 2;  // 16 KB
    unsigned short* Bpk  = (unsigned short*)(ws + off); off += (size_t)BB * 4096 * 2; // 256 KB
    unsigned* trigT = (unsigned*)(ws + off); off += (size_t)SS * 16 * 4;             // 4 MB
    const size_t CPL = (size_t)NSLOT * BB * 640;   // floats per layer-slot set

    dim3 gBS(SS / 256, BB);
    dim3 gBF(SS / 128, BB);

    k_prep<<<1538, 256, 0, stream>>>(pd, fc1w, fc1b, invmax, cP, w1Tg, trigT);
    k_fc0_dft<<<gBS, 256, 0, stream>>>(x, pd, fc0w, fc0b, invmax, trigT, h2, cP);

    for (int l = 0; l < 3; ++l) {
        const float* wre = (const float*)d_in[8 + 4 * l];
        const float* wim = (const float*)d_in[9 + 4 * l];
        const float* ww  = (const float*)d_in[10 + 4 * l];
        const float* wb  = (const float*)d_in[11 + 4 * l];
        k_mix<<<BB, 320, 0, stream>>>(cP + (size_t)l * CPL, wre, wim, ww, wb, cA, cB, Bpk);
        k_point_dft<<<gBS, 256, 0, stream>>>(h2, Bpk, trigT, cP + (size_t)(l + 1) * CPL);
    }
    {   // layer 3 fused with fc1/gelu/fc2
        const float* wre = (const float*)d_in[20];
        const float* wim = (const float*)d_in[21];
        const float* ww  = (const float*)d_in[22];
        const float* wb  = (const float*)d_in[23];
        k_mix<<<BB, 320, 0, stream>>>(cP + (size_t)3 * CPL, wre, wim, ww, wb, cA, cB, Bpk);
        k_point_final<<<gBF, 128, 0, stream>>>(h2, Bpk, w1Tg, fc2w, fc2b, trigT, (float*)d_out);
    }
}

// Round 11
// 506.699 us; speedup vs baseline: 1.0687x; 1.0687x over previous
//
#include <hip/hip_runtime.h>
#include <math.h>

#define BB 32
#define SS 65536
#define CC 20
#define NM 16
#define HH 128
#define SP 256   // DFT LDS row pitch (bf16 elems), XOR-chunk swizzled (R21)
#define WP 64    // hT row pitch (bf16 elems): 8x short8 payload, XOR-swizzled chunks
#define NSLOT 16

using short8  = __attribute__((ext_vector_type(8))) short;
using floatx4 = __attribute__((ext_vector_type(4))) float;
using floatx2 = __attribute__((ext_vector_type(2))) float;

__device__ __forceinline__ unsigned short f2bf(float f) {
    union { float f; unsigned u; } v; v.f = f;
    unsigned u = v.u;
    return (unsigned short)((u + 0x7FFFu + ((u >> 16) & 1u)) >> 16);   // RNE
}
__device__ __forceinline__ float bf2f(unsigned short h) {
    union { unsigned u; float f; } v; v.u = ((unsigned)h) << 16; return v.f;
}
__device__ __forceinline__ unsigned short f2bflo(float a) {
    return f2bf(a - bf2f(f2bf(a)));
}
__device__ __forceinline__ unsigned pk2(unsigned short lo, unsigned short hi) {
    return (unsigned)lo | ((unsigned)hi << 16);
}
__device__ __forceinline__ float asf(unsigned u) {
    union { unsigned u; float f; } v; v.u = u; return v.f;
}
// R23: hardware packed f32->bf16 RNE — 1 VALU op replaces 2x 4-op software RNE.
__device__ __forceinline__ unsigned cvtpk(float lo, float hi) {
    unsigned r;
    asm("v_cvt_pk_bf16_f32 %0, %1, %2" : "=v"(r) : "v"(lo), "v"(hi));
    return r;
}

// Tanh-form gelu, native exp2/rcp (R11). |delta| vs erf-gelu ~3e-4.
__device__ __forceinline__ float gelu_fast(float v) {
    float u = v * v;
    float inner = v * fmaf(0.0356774081f, u, 0.7978845608f);
    float e = __builtin_amdgcn_exp2f(inner * 2.8853900818f);
    float r = __builtin_amdgcn_rcpf(e + 1.0f);
    return fmaf(-v, r, v);
}

// R24 (kept only in k_point_dft — no spill there; R25 post-mortem: in
// k_point_final the floatx2 pair-alignment pressure caused 122MB scratch).
__device__ __forceinline__ floatx2 gelu2(floatx2 v) {
    floatx2 u = v * v;
    floatx2 inner = v * (u * 0.0356774081f + 0.7978845608f);
    floatx2 z = inner * 2.8853900818f;
    floatx2 e, r;
    e.x = __builtin_amdgcn_exp2f(z.x);
    e.y = __builtin_amdgcn_exp2f(z.y);
    r.x = __builtin_amdgcn_rcpf(e.x + 1.0f);
    r.y = __builtin_amdgcn_rcpf(e.y + 1.0f);
    return v - v * r;
}

// R20: exact 16-lane (DPP-row) sum via rotation reduce. row_ror:n = 0x120|n.
__device__ __forceinline__ float row16_sum(float p) {
    union { float f; int i; } v, w;
    v.f = p;
    w.i = __builtin_amdgcn_update_dpp(0, v.i, 0x121, 0xF, 0xF, true); v.f += w.f;
    w.i = __builtin_amdgcn_update_dpp(0, v.i, 0x122, 0xF, 0xF, true); v.f += w.f;
    w.i = __builtin_amdgcn_update_dpp(0, v.i, 0x124, 0xF, 0xF, true); v.f += w.f;
    w.i = __builtin_amdgcn_update_dpp(0, v.i, 0x128, 0xF, 0xF, true); v.f += w.f;
    return v.f;
}

// R21: swizzled sh_* addressing — row pitch 256 ushort (512B, pow2), 16B-chunk
// XOR on row&7. Bank cost of dft_phase b128 reads: 2-way max (free, m136).
__device__ __forceinline__ int swzi(int row, int scol) {   // ushort index
    return row * SP + ((((scol >> 3) ^ row) & 7) << 3) + (scol & 7);
}

// R19/R20: shared A-row staging — [h(20)|1|pad(11)|cm_hi(16)|sm_hi(16)],
// XOR-chunk swizzled. Chunks 4..7 come straight from the trig table row.
__device__ __forceinline__ void stage_A(unsigned short* AST, int tid,
                                        const unsigned* hw,
                                        uint4 tc0, uint4 tc1, uint4 ts0, uint4 ts1) {
    int sw = tid & 7;
    unsigned* base = (unsigned*)(AST + tid * 64);
    *(uint4*)(base + ((0 ^ sw) << 2)) = (uint4){hw[0], hw[1], hw[2], hw[3]};
    *(uint4*)(base + ((1 ^ sw) << 2)) = (uint4){hw[4], hw[5], hw[6], hw[7]};
    *(uint4*)(base + ((2 ^ sw) << 2)) = (uint4){hw[8], hw[9], 0x00003F80u, 0u};  // h16..19, ONE, 0
    *(uint4*)(base + ((3 ^ sw) << 2)) = (uint4){0u, 0u, 0u, 0u};
    *(uint4*)(base + ((4 ^ sw) << 2)) = tc0;
    *(uint4*)(base + ((5 ^ sw) << 2)) = tc1;
    *(uint4*)(base + ((6 ^ sw) << 2)) = ts0;
    *(uint4*)(base + ((7 ^ sw) << 2)) = ts1;
}

// ---------------- k_prep: max-reduce + zero cP + w1T + trig table ----------
__global__ __launch_bounds__(256) void k_prep(const float* __restrict__ pd,
                                              const float* __restrict__ w1,
                                              const float* __restrict__ b1f,
                                              float* __restrict__ invmax,
                                              float* __restrict__ cP,
                                              unsigned short* __restrict__ w1Tg,
                                              unsigned* __restrict__ trigT) {
    int bx = blockIdx.x;
    if (bx == 0) {
        __shared__ float red[256];
        int t = threadIdx.x;
        float m = -1e30f;
        for (int i = t; i < SS; i += 256) m = fmaxf(m, pd[i]);
        red[t] = m; __syncthreads();
        for (int off = 128; off > 0; off >>= 1) {
            if (t < off) red[t] = fmaxf(red[t], red[t + off]);
            __syncthreads();
        }
        if (t == 0) invmax[0] = 1.0f / red[0];
    } else if (bx <= 1280) {
        int idx = (bx - 1) * 256 + threadIdx.x;   // 1280*256 float4 = 4*16*32*640 floats
        float4 z = {0.f, 0.f, 0.f, 0.f};
        ((float4*)cP)[idx] = z;
    } else if (bx == 1281) {
        for (int idx = threadIdx.x; idx < HH * 64; idx += 256) {
            int j = idx >> 6, k = idx & 63;
            unsigned short r = 0;
            if (k < CC) r = f2bf(w1[k * HH + j]);
            else if (k == CC) r = f2bf(b1f[j]);
            else if (k >= 32 && k < 32 + CC) r = f2bflo(w1[(k - 32) * HH + j]);
            else if (k == 32 + CC) r = f2bflo(b1f[j]);
            w1Tg[idx] = r;
        }
    } else {   // bx in [1282, 1537]: trig table
        int s = (bx - 1282) * 256 + threadIdx.x;
        float u = (float)s * (1.0f / 32768.0f);
        float s1, c1; sincospif(u, &s1, &c1);
        float cm = 1.0f, sm = 0.0f;
        unsigned short ch[NM], sh[NM];
        #pragma unroll
        for (int m = 0; m < NM; ++m) {
            ch[m] = f2bf(cm); sh[m] = f2bf(sm);
            float cn = cm * c1 - sm * s1;
            sm = sm * c1 + cm * s1;
            cm = cn;
        }
        uint4* row = (uint4*)(trigT + (size_t)s * 16);
        row[0] = (uint4){pk2(ch[0],ch[1]), pk2(ch[2],ch[3]), pk2(ch[4],ch[5]), pk2(ch[6],ch[7])};
        row[1] = (uint4){pk2(ch[8],ch[9]), pk2(ch[10],ch[11]), pk2(ch[12],ch[13]), pk2(ch[14],ch[15])};
        row[2] = (uint4){pk2(sh[0],sh[1]), pk2(sh[2],sh[3]), pk2(sh[4],sh[5]), pk2(sh[6],sh[7])};
        row[3] = (uint4){pk2(sh[8],sh[9]), pk2(sh[10],sh[11]), pk2(sh[12],sh[13]), pk2(sh[14],sh[15])};
    }
}

// ---------------- shared DFT tail: LDS-staged MFMA partial DFT --------------
// R21: swizzled pitch-256 reads; (16+frow)&7 == frow&7 so one swizzle value.
__device__ __forceinline__ void dft_phase(unsigned short* sh_hA, unsigned short* sh_ph,
                                          int tid, float* cPdst) {
    int wave = tid >> 6, lane = tid & 63;
    int quad = lane >> 4, frow = lane & 15;
    floatx4 acc00 = {0.f,0.f,0.f,0.f}, acc01 = {0.f,0.f,0.f,0.f};
    floatx4 acc10 = {0.f,0.f,0.f,0.f}, acc11 = {0.f,0.f,0.f,0.f};
    int kb = wave * 64 + quad * 8;
    #pragma unroll
    for (int kc = 0; kc < 2; ++kc) {
        int k = kb + kc * 32;
        int co = (((k >> 3) ^ frow) & 7) << 3;     // swizzled chunk offset
        short8 a0 = *(const short8*)(sh_hA + frow * SP + co);
        short8 a1 = *(const short8*)(sh_hA + (16 + frow) * SP + co);
        short8 bc = *(const short8*)(sh_ph + frow * SP + co);
        short8 bs = *(const short8*)(sh_ph + (16 + frow) * SP + co);
        acc00 = __builtin_amdgcn_mfma_f32_16x16x32_bf16(a0, bc, acc00, 0, 0, 0);
        acc01 = __builtin_amdgcn_mfma_f32_16x16x32_bf16(a0, bs, acc01, 0, 0, 0);
        acc10 = __builtin_amdgcn_mfma_f32_16x16x32_bf16(a1, bc, acc10, 0, 0, 0);
        acc11 = __builtin_amdgcn_mfma_f32_16x16x32_bf16(a1, bs, acc11, 0, 0, 0);
    }
    __syncthreads();
    float* red = (float*)sh_hA;
    #pragma unroll
    for (int r = 0; r < 4; ++r) {
        red[wave * 1024 + 0 * 256 + r * 64 + lane] = acc00[r];
        red[wave * 1024 + 1 * 256 + r * 64 + lane] = acc01[r];
        red[wave * 1024 + 2 * 256 + r * 64 + lane] = acc10[r];
        red[wave * 1024 + 3 * 256 + r * 64 + lane] = acc11[r];
    }
    __syncthreads();
    #pragma unroll
    for (int ii = 0; ii < 4; ++ii) {
        int idx = ii * 256 + tid;
        float v = red[idx] + red[1024 + idx] + red[2048 + idx] + red[3072 + idx];
        int f = idx >> 8;
        int r = (idx >> 6) & 3, ln = idx & 63;
        int o = (f >> 1) * 16 + (ln >> 4) * 4 + r;   // D row = quad*4+reg
        int m = ln & 15;                              // D col = lane&15
        if (o < CC) atomicAdd(cPdst + (f & 1) * 320 + o * 16 + m, v);
    }
}

// ---------------- k_fc0_dft: h2 (paired bf16 dwords) = fc0; DFT partials ----
// R22 bounds (256,4); R23 cvt_pk; R24 packed-f32 affine math (no spill here).
__global__ __launch_bounds__(256, 4) void k_fc0_dft(const float* __restrict__ x,
        const float* __restrict__ pd, const float* __restrict__ w,
        const float* __restrict__ bias, const float* __restrict__ invmax,
        const unsigned* __restrict__ trigT,
        unsigned* __restrict__ h2, float* __restrict__ cP0) {
    __shared__ __align__(16) unsigned short LB[2 * 32 * SP];   // 32768 B exactly
    unsigned short* sh_hA = LB;
    unsigned short* sh_ph = LB + 32 * SP;
    int tid = threadIdx.x;
    {
        unsigned* z = (unsigned*)(sh_hA + CC * SP);
        for (int i = tid; i < (32 - CC) * SP / 2; i += 256) z[i] = 0;
    }
    int b = blockIdx.y;
    int s = blockIdx.x * 256 + tid;
    float xv = x[(size_t)b * SS + s];
    float g  = pd[s] * invmax[0];
    unsigned* hp2 = h2 + (size_t)b * (CC / 2) * SS + s;
    const uint4* trow = (const uint4*)(trigT + (size_t)s * 16);
    uint4 tc0 = trow[0], tc1 = trow[1], ts0 = trow[2], ts1 = trow[3];
    unsigned c8[8] = {tc0.x, tc0.y, tc0.z, tc0.w, tc1.x, tc1.y, tc1.z, tc1.w};
    unsigned s8[8] = {ts0.x, ts0.y, ts0.z, ts0.w, ts1.x, ts1.y, ts1.z, ts1.w};
    #pragma unroll
    for (int m = 0; m < NM; ++m) {
        unsigned cd = c8[m >> 1], sd = s8[m >> 1];
        sh_ph[swzi(m, tid)]      = (unsigned short)((m & 1) ? (cd >> 16) : (cd & 0xFFFFu));
        sh_ph[swzi(16 + m, tid)] = (unsigned short)((m & 1) ? (sd >> 16) : (sd & 0xFFFFu));
    }
    #pragma unroll
    for (int p = 0; p < CC / 2; ++p) {
        int c0 = 2 * p, c1i = 2 * p + 1;
        // R24: packed affine (scalar s_loads stay scalar — R15 lesson)
        floatx2 wv = {w[c0], w[c1i]};
        floatx2 gv = {w[CC + c0], w[CC + c1i]};
        floatx2 bv = {bias[c0], bias[c1i]};
        floatx2 v = wv * xv + gv * g + bv;
        unsigned dw = cvtpk(v.x, v.y);                 // R23: HW RNE pair
        hp2[(size_t)p * SS] = dw;
        sh_hA[swzi(c0, tid)]  = (unsigned short)(dw & 0xFFFFu);
        sh_hA[swzi(c1i, tid)] = (unsigned short)(dw >> 16);
    }
    __syncthreads();
    dft_phase(sh_hA, sh_ph, tid, cP0 + ((size_t)(blockIdx.x & (NSLOT - 1)) * BB + b) * 640);
}

// ---------------- k_point_dft (layers 0..2): MFMA point-op + next-layer DFT -
// R19 structure + R20 trig table + R21 swizzle + R22 bounds + R23 cvt_pk +
// R24 gelu2 (no spill signature in this kernel).
__global__ __launch_bounds__(256, 4) void k_point_dft(unsigned* __restrict__ h2,
        const unsigned short* __restrict__ Bpk,
        const unsigned* __restrict__ trigT,
        float* __restrict__ cPn) {
    __shared__ __align__(16) unsigned short LB[2 * 32 * SP];   // 32768 B exactly
    unsigned short* AST   = LB;                  // 32 KB staged A-rows (all of LB)
    unsigned short* sh_hA = LB;                  // aliases, valid after barrier
    unsigned short* sh_ph = LB + 32 * SP;
    int tid = threadIdx.x;
    int b = blockIdx.y;
    int s = blockIdx.x * 256 + tid;

    // ---- phase A: table load + old-h load + A-row staging (wave-local) ----
    const uint4* trow = (const uint4*)(trigT + (size_t)s * 16);
    uint4 tc0 = trow[0], tc1 = trow[1], ts0 = trow[2], ts1 = trow[3];
    const unsigned* hp2r = h2 + (size_t)b * (CC / 2) * SS + s;
    unsigned hw[CC / 2];
    #pragma unroll
    for (int p = 0; p < CC / 2; ++p) hw[p] = hp2r[(size_t)p * SS];
    stage_A(AST, tid, hw, tc0, tc1, ts0, ts1);
    // no barrier: phase B reads only this wave's rows, written by this wave

    // ---- phase B: MFMA point-op (swapped), gelu, in-lane pack, h2 -----
    int wave = tid >> 6, lane = tid & 63, col = lane & 15, quad = lane >> 4;
    const unsigned short* Bp = Bpk + (size_t)b * 4096;
    short8 wh0[2], wh1[2], wl0[2], wl1[2];
    #pragma unroll
    for (int cht = 0; cht < 2; ++cht) {
        int o = cht * 16 + col;
        wh0[cht] = *(const short8*)(Bp + o * 64 + quad * 8);
        wh1[cht] = *(const short8*)(Bp + o * 64 + 32 + quad * 8);
        wl0[cht] = *(const short8*)(Bp + 2048 + o * 64 + quad * 8);
        wl1[cht] = *(const short8*)(Bp + 2048 + o * 64 + 32 + quad * 8);
    }
    unsigned* h2b = h2 + (size_t)b * (CC / 2) * SS + blockIdx.x * 256;
    unsigned pkr[2][4][2];
    #pragma unroll
    for (int st = 0; st < 4; ++st) {
        int ar = wave * 64 + st * 16 + col;
        int sw = ar & 7;
        const unsigned short* abase = AST + ar * 64;
        short8 ah0 = *(const short8*)(abase + ((quad ^ sw) << 3));
        short8 ah1 = *(const short8*)(abase + (((4 + quad) ^ sw) << 3));
        #pragma unroll
        for (int cht = 0; cht < 2; ++cht) {
            floatx4 a = {0.f, 0.f, 0.f, 0.f};
            a = __builtin_amdgcn_mfma_f32_16x16x32_bf16(wh0[cht], ah0, a, 0, 0, 0);
            a = __builtin_amdgcn_mfma_f32_16x16x32_bf16(wh1[cht], ah1, a, 0, 0, 0);
            a = __builtin_amdgcn_mfma_f32_16x16x32_bf16(wl0[cht], ah0, a, 0, 0, 0);
            a = __builtin_amdgcn_mfma_f32_16x16x32_bf16(wl1[cht], ah1, a, 0, 0, 0);
            floatx2 g01 = gelu2((floatx2){a[0], a[1]});   // R24
            floatx2 g23 = gelu2((floatx2){a[2], a[3]});
            unsigned d0 = cvtpk(g01.x, g01.y);
            unsigned d1 = cvtpk(g23.x, g23.y);
            pkr[cht][st][0] = d0;
            pkr[cht][st][1] = d1;
            int p = cht * 8 + quad * 2;               // channel pair index
            if (p < CC / 2) {                          // cht1: quad0 only
                h2b[(size_t)p * SS + ar]       = d0;
                h2b[(size_t)(p + 1) * SS + ar] = d1;
            }
        }
    }
    __syncthreads();   // all waves' AST reads done; LDS becomes sh_hA/sh_ph

    // ---- phase C: scatter h_new to sh_hA, write sh_ph from table ------
    {
        unsigned* z = (unsigned*)(sh_hA + CC * SP);
        #pragma unroll
        for (int i = tid; i < (32 - CC) * SP / 2; i += 256) z[i] = 0;
    }
    {
        unsigned c8[8] = {tc0.x, tc0.y, tc0.z, tc0.w, tc1.x, tc1.y, tc1.z, tc1.w};
        unsigned s8[8] = {ts0.x, ts0.y, ts0.z, ts0.w, ts1.x, ts1.y, ts1.z, ts1.w};
        #pragma unroll
        for (int m = 0; m < NM; ++m) {
            unsigned cd = c8[m >> 1], sd = s8[m >> 1];
            sh_ph[swzi(m, tid)]      = (unsigned short)((m & 1) ? (cd >> 16) : (cd & 0xFFFFu));
            sh_ph[swzi(16 + m, tid)] = (unsigned short)((m & 1) ? (sd >> 16) : (sd & 0xFFFFu));
        }
    }
    #pragma unroll
    for (int cht = 0; cht < 2; ++cht) {
        int ob = cht * 16 + quad * 4;
        if (ob < CC) {
            #pragma unroll
            for (int st = 0; st < 4; ++st) {
                int s_loc = wave * 64 + st * 16 + col;
                #pragma unroll
                for (int rp = 0; rp < 2; ++rp) {
                    unsigned d = pkr[cht][st][rp];
                    sh_hA[swzi(ob + 2 * rp, s_loc)]     = (unsigned short)(d & 0xFFFFu);
                    sh_hA[swzi(ob + 2 * rp + 1, s_loc)] = (unsigned short)(d >> 16);
                }
            }
        }
    }
    __syncthreads();
    dft_phase(sh_hA, sh_ph, tid, cPn + ((size_t)(blockIdx.x & (NSLOT - 1)) * BB + b) * 640);
}

// ---------------- k_mix: partial reduce + complex mixing + B-panel pack -----
__global__ __launch_bounds__(320) void k_mix(const float* __restrict__ cP,
                                             const float* __restrict__ wre, const float* __restrict__ wim,
                                             const float* __restrict__ ww, const float* __restrict__ wb,
                                             float* __restrict__ cA, float* __restrict__ cB,
                                             unsigned short* __restrict__ Bpk) {
    int b = blockIdx.x, tid = threadIdx.x;
    __shared__ float PQ[640];
    const float* base = cP + (size_t)b * 640;
    int i = tid >> 4, m = tid & 15;
    float sP = 0.f, sQ = 0.f;
    #pragma unroll 4
    for (int sl = 0; sl < NSLOT; ++sl) {
        sP += base[(size_t)sl * BB * 640 + tid];
        sQ += base[(size_t)sl * BB * 640 + 320 + tid];
    }
    PQ[i * 32 + m]      = sP;
    PQ[i * 32 + 16 + m] = sQ;
    __syncthreads();
    int o = i;
    float reY = 0.f, imY = 0.f;
    #pragma unroll
    for (int c = 0; c < CC; ++c) {
        float P = PQ[c * 32 + m], Q = PQ[c * 32 + 16 + m];
        float wr = wre[(size_t)(c * CC + o) * NM + m];
        float wi = wim[(size_t)(c * CC + o) * NM + m];
        reY += P * wr + Q * wi;                // X = P - iQ
        imY += P * wi - Q * wr;
    }
    const float invS = 1.0f / (float)SS;
    float a, bb;
    if (m == 0) { a = reY * invS; bb = 0.0f; } // irfft drops Im(DC)
    else        { a = 2.0f * reY * invS; bb = -2.0f * imY * invS; }
    cA[(size_t)(b * CC + o) * NM + m] = a;
    cB[(size_t)(b * CC + o) * NM + m] = bb;

    // ---- pack B panels for the MFMA point-op (per-b) ------------------
    unsigned short* Bp = Bpk + (size_t)b * 4096;
    for (int idx = tid; idx < 640; idx += 320) {       // o<20, k 0..31
        int o8 = idx >> 5, k = idx & 31;
        float v = 0.f;
        if (k < CC) v = ww[o8 * CC + k];
        else if (k == CC) v = wb[o8];
        Bp[o8 * 64 + k]        = f2bf(v);
        Bp[2048 + o8 * 64 + k] = f2bflo(v);
    }
    for (int idx = tid; idx < 768; idx += 320) {       // o 20..31: zero rows
        int o8 = 20 + (idx >> 6), k = idx & 63;
        Bp[o8 * 64 + k] = 0;
        Bp[2048 + o8 * 64 + k] = 0;
    }
    Bp[o * 64 + 32 + m]        = f2bf(a);
    Bp[o * 64 + 48 + m]        = f2bf(bb);
    Bp[2048 + o * 64 + 32 + m] = f2bflo(a);
    Bp[2048 + o * 64 + 48 + m] = f2bflo(bb);
}

// ---------------- k_point_final: MFMA layer-3 point op + fc1 + gelu + fc2 ---
// R22 geometry (128 threads, hT 16 KB); R23 cvt_pk. R25: exact R23 body —
// R24's floatx2 rewrite here spilled 122MB scratch (pair-alignment pressure);
// scalar gelu_fast + scalar accumulators is the no-spill form.
__global__ __launch_bounds__(128, 4) void k_point_final(const unsigned* __restrict__ h2,
        const unsigned short* __restrict__ Bpk,
        const unsigned short* __restrict__ w1Tg,
        const float* __restrict__ w2, const float* __restrict__ b2,
        const unsigned* __restrict__ trigT,
        float* __restrict__ out) {
    __shared__ __align__(16) unsigned short AST[128 * 64];   // 16384 B
    unsigned short* hT = AST;            // aliased, wave-local throughout
    int tid = threadIdx.x;
    int b = blockIdx.y;
    int s = blockIdx.x * 128 + tid;

    // ---- phase A: table load + h load + A-row staging -----------------
    const uint4* trow = (const uint4*)(trigT + (size_t)s * 16);
    uint4 tc0 = trow[0], tc1 = trow[1], ts0 = trow[2], ts1 = trow[3];
    const unsigned* hp2r = h2 + (size_t)b * (CC / 2) * SS + s;
    unsigned hw[CC / 2];
    #pragma unroll
    for (int p = 0; p < CC / 2; ++p) hw[p] = hp2r[(size_t)p * SS];
    stage_A(AST, tid, hw, tc0, tc1, ts0, ts1);
    // no barrier: wave-local

    // ---- phase B: point-op MFMA (swapped, no gelu) --------------------
    int wave = tid >> 6, lane = tid & 63, col = lane & 15, quad = lane >> 4;
    const unsigned short* Bp = Bpk + (size_t)b * 4096;
    short8 wh0[2], wh1[2], wl0[2], wl1[2];
    #pragma unroll
    for (int cht = 0; cht < 2; ++cht) {
        int o = cht * 16 + col;
        wh0[cht] = *(const short8*)(Bp + o * 64 + quad * 8);
        wh1[cht] = *(const short8*)(Bp + o * 64 + 32 + quad * 8);
        wl0[cht] = *(const short8*)(Bp + 2048 + o * 64 + quad * 8);
        wl1[cht] = *(const short8*)(Bp + 2048 + o * 64 + 32 + quad * 8);
    }
    float res[2][4][4];   // [cht][st][r] — statically indexed
    #pragma unroll
    for (int st = 0; st < 4; ++st) {
        int ar = wave * 64 + st * 16 + col;
        int sw = ar & 7;
        const unsigned short* abase = AST + ar * 64;
        short8 ah0 = *(const short8*)(abase + ((quad ^ sw) << 3));
        short8 ah1 = *(const short8*)(abase + (((4 + quad) ^ sw) << 3));
        #pragma unroll
        for (int cht = 0; cht < 2; ++cht) {
            floatx4 a = {0.f, 0.f, 0.f, 0.f};
            a = __builtin_amdgcn_mfma_f32_16x16x32_bf16(wh0[cht], ah0, a, 0, 0, 0);
            a = __builtin_amdgcn_mfma_f32_16x16x32_bf16(wh1[cht], ah1, a, 0, 0, 0);
            a = __builtin_amdgcn_mfma_f32_16x16x32_bf16(wl0[cht], ah0, a, 0, 0, 0);
            a = __builtin_amdgcn_mfma_f32_16x16x32_bf16(wl1[cht], ah1, a, 0, 0, 0);
            #pragma unroll
            for (int r = 0; r < 4; ++r) res[cht][st][r] = a[r];
        }
    }
    // no barrier: phase C writes this wave's own rows only

    // ---- phase C: in-lane hi/lo cvt_pk into hT; dwi==10 = (ONE,0) slot ----
    #pragma unroll
    for (int cht = 0; cht < 2; ++cht) {
        #pragma unroll
        for (int st = 0; st < 4; ++st) {
            int row = wave * 64 + st * 16 + col;
            int sw = row & 7;
            unsigned* rb = (unsigned*)(hT + row * WP);
            #pragma unroll
            for (int rp = 0; rp < 2; ++rp) {
                int dwi = cht * 8 + quad * 2 + rp;
                if (dwi <= CC / 2) {                   // 10 = bias ONE slot
                    float f0, f1;
                    if (dwi == CC / 2) { f0 = 1.0f; f1 = 0.0f; }
                    else { f0 = res[cht][st][2 * rp]; f1 = res[cht][st][2 * rp + 1]; }
                    unsigned hd = cvtpk(f0, f1);                      // R23
                    float r0 = asf(hd << 16), r1 = asf(hd & 0xFFFF0000u);
                    unsigned ld = cvtpk(f0 - r0, f1 - r1);
                    int chunk = dwi >> 2, pos = dwi & 3;
                    rb[((chunk ^ sw) << 2) + pos]       = hd;
                    rb[(((chunk + 4) ^ sw) << 2) + pos] = ld;
                }
            }
        }
    }
    // no barrier: fc1 reads this wave's own rows only

    // ---- fc1 MFMA (bias in MFMA) + gelu + fc2 --------------------------
    short8 bhi[8], blo[8];
    #pragma unroll
    for (int nt = 0; nt < 8; ++nt) {
        bhi[nt] = *(const short8*)(w1Tg + (size_t)(nt * 16 + col) * 64 + quad * 8);
        blo[nt] = *(const short8*)(w1Tg + (size_t)(nt * 16 + col) * 64 + 32 + quad * 8);
    }
    float w2r[8];
    #pragma unroll
    for (int nt = 0; nt < 8; ++nt) w2r[nt] = w2[nt * 16 + col];
    float b2v = b2[0];
    #pragma unroll
    for (int mt = 0; mt < 4; ++mt) {
        int srow = wave * 64 + mt * 16 + col;     // A row m = lane&15
        int sw = srow & 7;
        short8 ahi = *(const short8*)(hT + srow * WP + ((quad ^ sw) << 3));
        short8 alo = *(const short8*)(hT + srow * WP + (((quad ^ sw) ^ 4) << 3));
        float part[4] = {0.f, 0.f, 0.f, 0.f};
        #pragma unroll
        for (int nt = 0; nt < 8; ++nt) {
            floatx4 a = {0.f, 0.f, 0.f, 0.f};
            a = __builtin_amdgcn_mfma_f32_16x16x32_bf16(ahi, bhi[nt], a, 0, 0, 0);
            a = __builtin_amdgcn_mfma_f32_16x16x32_bf16(ahi, blo[nt], a, 0, 0, 0);
            a = __builtin_amdgcn_mfma_f32_16x16x32_bf16(alo, bhi[nt], a, 0, 0, 0);
            #pragma unroll
            for (int r = 0; r < 4; ++r) {
                float t = gelu_fast(a[r]);
                part[r] += t * w2r[nt];
            }
        }
        #pragma unroll
        for (int r = 0; r < 4; ++r) {
            float p = row16_sum(part[r]);
            if (col == 0) {
                int row = wave * 64 + mt * 16 + quad * 4 + r;   // dead rows of this tile
                *(float*)(&hT[row * WP + ((row & 7) << 3)]) = p + b2v;
            }
        }
    }
    __syncthreads();      // the single cross-wave hand-off
    out[(size_t)b * SS + blockIdx.x * 128 + tid] = *(const float*)(&hT[tid * WP + ((tid & 7) << 3)]);
}

extern "C" void kernel_launch(void* const* d_in, const int* in_sizes, int n_in,
                              void* d_out, int out_size, void* d_ws, size_t ws_size,
                              hipStream_t stream) {
    (void)in_sizes; (void)n_in; (void)out_size; (void)ws_size;
    const float* x    = (const float*)d_in[0];
    const float* pd   = (const float*)d_in[1];
    const float* fc0w = (const float*)d_in[2];
    const float* fc0b = (const float*)d_in[3];
    const float* fc1w = (const float*)d_in[4];
    const float* fc1b = (const float*)d_in[5];
    const float* fc2w = (const float*)d_in[6];
    const float* fc2b = (const float*)d_in[7];

    char* ws = (char*)d_ws;
    unsigned* h2 = (unsigned*)ws;
    size_t off = (size_t)BB * (CC / 2) * SS * 4;                      // 83.9 MB (paired bf16)
    float* cP = (float*)(ws + off); off += (size_t)4 * NSLOT * BB * 640 * 4;  // 5.24 MB
    float* cA = (float*)(ws + off); off += (size_t)BB * CC * NM * 4;
    float* cB = (float*)(ws + off); off += (size_t)BB * CC * NM * 4;
    float* invmax = (float*)(ws + off); off += 256;
    unsigned short* w1Tg = (unsigned short*)(ws + off); off += (size_t)HH * 64 * 2;  // 16 KB
    unsigned short* Bpk  = (unsigned short*)(ws + off); off += (size_t)BB * 4096 * 2; // 256 KB
    unsigned* trigT = (unsigned*)(ws + off); off += (size_t)SS * 16 * 4;             // 4 MB
    const size_t CPL = (size_t)NSLOT * BB * 640;   // floats per layer-slot set

    dim3 gBS(SS / 256, BB);
    dim3 gBF(SS / 128, BB);

    k_prep<<<1538, 256, 0, stream>>>(pd, fc1w, fc1b, invmax, cP, w1Tg, trigT);
    k_fc0_dft<<<gBS, 256, 0, stream>>>(x, pd, fc0w, fc0b, invmax, trigT, h2, cP);

    for (int l = 0; l < 3; ++l) {
        const float* wre = (const float*)d_in[8 + 4 * l];
        const float* wim = (const float*)d_in[9 + 4 * l];
        const float* ww  = (const float*)d_in[10 + 4 * l];
        const float* wb  = (const float*)d_in[11 + 4 * l];
        k_mix<<<BB, 320, 0, stream>>>(cP + (size_t)l * CPL, wre, wim, ww, wb, cA, cB, Bpk);
        k_point_dft<<<gBS, 256, 0, stream>>>(h2, Bpk, trigT, cP + (size_t)(l + 1) * CPL);
    }
    {   // layer 3 fused with fc1/gelu/fc2
        const float* wre = (const float*)d_in[20];
        const float* wim = (const float*)d_in[21];
        const float* ww  = (const float*)d_in[22];
        const float* wb  = (const float*)d_in[23];
        k_mix<<<BB, 320, 0, stream>>>(cP + (size_t)3 * CPL, wre, wim, ww, wb, cA, cB, Bpk);
        k_point_final<<<gBF, 128, 0, stream>>>(h2, Bpk, w1Tg, fc2w, fc2b, trigT, (float*)d_out);
    }
}

// Round 12
// 505.426 us; speedup vs baseline: 1.0714x; 1.0025x over previous
//
#include <hip/hip_runtime.h>
#include <math.h>

#define BB 32
#define SS 65536
#define CC 20
#define NM 16
#define HH 128
#define SP 256   // DFT LDS row pitch (bf16 elems), XOR-chunk swizzled (R21)
#define WP 64    // hT row pitch (bf16 elems): 8x short8 payload, XOR-swizzled chunks
#define NSLOT 16
#define HREC 12  // R26: h2 record stride in dwords (10 used, 48B aligned)

using short8  = __attribute__((ext_vector_type(8))) short;
using floatx4 = __attribute__((ext_vector_type(4))) float;
using floatx2 = __attribute__((ext_vector_type(2))) float;

__device__ __forceinline__ unsigned short f2bf(float f) {
    union { float f; unsigned u; } v; v.f = f;
    unsigned u = v.u;
    return (unsigned short)((u + 0x7FFFu + ((u >> 16) & 1u)) >> 16);   // RNE
}
__device__ __forceinline__ float bf2f(unsigned short h) {
    union { unsigned u; float f; } v; v.u = ((unsigned)h) << 16; return v.f;
}
__device__ __forceinline__ unsigned short f2bflo(float a) {
    return f2bf(a - bf2f(f2bf(a)));
}
__device__ __forceinline__ unsigned pk2(unsigned short lo, unsigned short hi) {
    return (unsigned)lo | ((unsigned)hi << 16);
}
__device__ __forceinline__ float asf(unsigned u) {
    union { unsigned u; float f; } v; v.u = u; return v.f;
}
// R23: hardware packed f32->bf16 RNE — 1 VALU op replaces 2x 4-op software RNE.
__device__ __forceinline__ unsigned cvtpk(float lo, float hi) {
    unsigned r;
    asm("v_cvt_pk_bf16_f32 %0, %1, %2" : "=v"(r) : "v"(lo), "v"(hi));
    return r;
}

// Tanh-form gelu, native exp2/rcp (R11). |delta| vs erf-gelu ~3e-4.
__device__ __forceinline__ float gelu_fast(float v) {
    float u = v * v;
    float inner = v * fmaf(0.0356774081f, u, 0.7978845608f);
    float e = __builtin_amdgcn_exp2f(inner * 2.8853900818f);
    float r = __builtin_amdgcn_rcpf(e + 1.0f);
    return fmaf(-v, r, v);
}

// R24 (kept only in k_point_dft — no spill there; R25 post-mortem: in
// k_point_final the floatx2 pair-alignment pressure caused 122MB scratch).
__device__ __forceinline__ floatx2 gelu2(floatx2 v) {
    floatx2 u = v * v;
    floatx2 inner = v * (u * 0.0356774081f + 0.7978845608f);
    floatx2 z = inner * 2.8853900818f;
    floatx2 e, r;
    e.x = __builtin_amdgcn_exp2f(z.x);
    e.y = __builtin_amdgcn_exp2f(z.y);
    r.x = __builtin_amdgcn_rcpf(e.x + 1.0f);
    r.y = __builtin_amdgcn_rcpf(e.y + 1.0f);
    return v - v * r;
}

// R20: exact 16-lane (DPP-row) sum via rotation reduce. row_ror:n = 0x120|n.
__device__ __forceinline__ float row16_sum(float p) {
    union { float f; int i; } v, w;
    v.f = p;
    w.i = __builtin_amdgcn_update_dpp(0, v.i, 0x121, 0xF, 0xF, true); v.f += w.f;
    w.i = __builtin_amdgcn_update_dpp(0, v.i, 0x122, 0xF, 0xF, true); v.f += w.f;
    w.i = __builtin_amdgcn_update_dpp(0, v.i, 0x124, 0xF, 0xF, true); v.f += w.f;
    w.i = __builtin_amdgcn_update_dpp(0, v.i, 0x128, 0xF, 0xF, true); v.f += w.f;
    return v.f;
}

// R21: swizzled sh_* addressing — row pitch 256 ushort (512B, pow2), 16B-chunk
// XOR on row&7. Bank cost of dft_phase b128 reads: 2-way max (free, m136).
__device__ __forceinline__ int swzi(int row, int scol) {   // ushort index
    return row * SP + ((((scol >> 3) ^ row) & 7) << 3) + (scol & 7);
}

// R19/R20: shared A-row staging — [h(20)|1|pad(11)|cm_hi(16)|sm_hi(16)],
// XOR-chunk swizzled. Chunks 4..7 come straight from the trig table row.
__device__ __forceinline__ void stage_A(unsigned short* AST, int tid,
                                        const unsigned* hw,
                                        uint4 tc0, uint4 tc1, uint4 ts0, uint4 ts1) {
    int sw = tid & 7;
    unsigned* base = (unsigned*)(AST + tid * 64);
    *(uint4*)(base + ((0 ^ sw) << 2)) = (uint4){hw[0], hw[1], hw[2], hw[3]};
    *(uint4*)(base + ((1 ^ sw) << 2)) = (uint4){hw[4], hw[5], hw[6], hw[7]};
    *(uint4*)(base + ((2 ^ sw) << 2)) = (uint4){hw[8], hw[9], 0x00003F80u, 0u};  // h16..19, ONE, 0
    *(uint4*)(base + ((3 ^ sw) << 2)) = (uint4){0u, 0u, 0u, 0u};
    *(uint4*)(base + ((4 ^ sw) << 2)) = tc0;
    *(uint4*)(base + ((5 ^ sw) << 2)) = tc1;
    *(uint4*)(base + ((6 ^ sw) << 2)) = ts0;
    *(uint4*)(base + ((7 ^ sw) << 2)) = ts1;
}

// ---------------- k_prep: max-reduce + zero cP + w1T + trig table ----------
__global__ __launch_bounds__(256) void k_prep(const float* __restrict__ pd,
                                              const float* __restrict__ w1,
                                              const float* __restrict__ b1f,
                                              float* __restrict__ invmax,
                                              float* __restrict__ cP,
                                              unsigned short* __restrict__ w1Tg,
                                              unsigned* __restrict__ trigT) {
    int bx = blockIdx.x;
    if (bx == 0) {
        __shared__ float red[256];
        int t = threadIdx.x;
        float m = -1e30f;
        for (int i = t; i < SS; i += 256) m = fmaxf(m, pd[i]);
        red[t] = m; __syncthreads();
        for (int off = 128; off > 0; off >>= 1) {
            if (t < off) red[t] = fmaxf(red[t], red[t + off]);
            __syncthreads();
        }
        if (t == 0) invmax[0] = 1.0f / red[0];
    } else if (bx <= 1280) {
        int idx = (bx - 1) * 256 + threadIdx.x;   // 1280*256 float4 = 4*16*32*640 floats
        float4 z = {0.f, 0.f, 0.f, 0.f};
        ((float4*)cP)[idx] = z;
    } else if (bx == 1281) {
        for (int idx = threadIdx.x; idx < HH * 64; idx += 256) {
            int j = idx >> 6, k = idx & 63;
            unsigned short r = 0;
            if (k < CC) r = f2bf(w1[k * HH + j]);
            else if (k == CC) r = f2bf(b1f[j]);
            else if (k >= 32 && k < 32 + CC) r = f2bflo(w1[(k - 32) * HH + j]);
            else if (k == 32 + CC) r = f2bflo(b1f[j]);
            w1Tg[idx] = r;
        }
    } else {   // bx in [1282, 1537]: trig table
        int s = (bx - 1282) * 256 + threadIdx.x;
        float u = (float)s * (1.0f / 32768.0f);
        float s1, c1; sincospif(u, &s1, &c1);
        float cm = 1.0f, sm = 0.0f;
        unsigned short ch[NM], sh[NM];
        #pragma unroll
        for (int m = 0; m < NM; ++m) {
            ch[m] = f2bf(cm); sh[m] = f2bf(sm);
            float cn = cm * c1 - sm * s1;
            sm = sm * c1 + cm * s1;
            cm = cn;
        }
        uint4* row = (uint4*)(trigT + (size_t)s * 16);
        row[0] = (uint4){pk2(ch[0],ch[1]), pk2(ch[2],ch[3]), pk2(ch[4],ch[5]), pk2(ch[6],ch[7])};
        row[1] = (uint4){pk2(ch[8],ch[9]), pk2(ch[10],ch[11]), pk2(ch[12],ch[13]), pk2(ch[14],ch[15])};
        row[2] = (uint4){pk2(sh[0],sh[1]), pk2(sh[2],sh[3]), pk2(sh[4],sh[5]), pk2(sh[6],sh[7])};
        row[3] = (uint4){pk2(sh[8],sh[9]), pk2(sh[10],sh[11]), pk2(sh[12],sh[13]), pk2(sh[14],sh[15])};
    }
}

// ---------------- shared DFT tail: LDS-staged MFMA partial DFT --------------
// R21: swizzled pitch-256 reads; (16+frow)&7 == frow&7 so one swizzle value.
// R26 note: sh_hA rows 20..31 may hold GARBAGE — MFMA rows don't mix, so only
// D-channels 20..31 are corrupted, and the o<CC predicate discards them.
__device__ __forceinline__ void dft_phase(unsigned short* sh_hA, unsigned short* sh_ph,
                                          int tid, float* cPdst) {
    int wave = tid >> 6, lane = tid & 63;
    int quad = lane >> 4, frow = lane & 15;
    floatx4 acc00 = {0.f,0.f,0.f,0.f}, acc01 = {0.f,0.f,0.f,0.f};
    floatx4 acc10 = {0.f,0.f,0.f,0.f}, acc11 = {0.f,0.f,0.f,0.f};
    int kb = wave * 64 + quad * 8;
    #pragma unroll
    for (int kc = 0; kc < 2; ++kc) {
        int k = kb + kc * 32;
        int co = (((k >> 3) ^ frow) & 7) << 3;     // swizzled chunk offset
        short8 a0 = *(const short8*)(sh_hA + frow * SP + co);
        short8 a1 = *(const short8*)(sh_hA + (16 + frow) * SP + co);
        short8 bc = *(const short8*)(sh_ph + frow * SP + co);
        short8 bs = *(const short8*)(sh_ph + (16 + frow) * SP + co);
        acc00 = __builtin_amdgcn_mfma_f32_16x16x32_bf16(a0, bc, acc00, 0, 0, 0);
        acc01 = __builtin_amdgcn_mfma_f32_16x16x32_bf16(a0, bs, acc01, 0, 0, 0);
        acc10 = __builtin_amdgcn_mfma_f32_16x16x32_bf16(a1, bc, acc10, 0, 0, 0);
        acc11 = __builtin_amdgcn_mfma_f32_16x16x32_bf16(a1, bs, acc11, 0, 0, 0);
    }
    __syncthreads();
    float* red = (float*)sh_hA;
    #pragma unroll
    for (int r = 0; r < 4; ++r) {
        red[wave * 1024 + 0 * 256 + r * 64 + lane] = acc00[r];
        red[wave * 1024 + 1 * 256 + r * 64 + lane] = acc01[r];
        red[wave * 1024 + 2 * 256 + r * 64 + lane] = acc10[r];
        red[wave * 1024 + 3 * 256 + r * 64 + lane] = acc11[r];
    }
    __syncthreads();
    #pragma unroll
    for (int ii = 0; ii < 4; ++ii) {
        int idx = ii * 256 + tid;
        float v = red[idx] + red[1024 + idx] + red[2048 + idx] + red[3072 + idx];
        int f = idx >> 8;
        int r = (idx >> 6) & 3, ln = idx & 63;
        int o = (f >> 1) * 16 + (ln >> 4) * 4 + r;   // D row = quad*4+reg
        int m = ln & 15;                              // D col = lane&15
        if (o < CC) atomicAdd(cPdst + (f & 1) * 320 + o * 16 + m, v);
    }
}

// ---------------- k_fc0_dft: h2 (record-major bf16 pairs) = fc0; DFT partials
// R26: h2 record [s][12 dwords] — own-s dwords contiguous: 2x uint4 + 1x uint2
// stores replace 10 strided dword stores (+their per-plane address math).
// Zero-fill of sh_hA rows 20..31 dropped (garbage channels are discarded).
__global__ __launch_bounds__(256, 4) void k_fc0_dft(const float* __restrict__ x,
        const float* __restrict__ pd, const float* __restrict__ w,
        const float* __restrict__ bias, const float* __restrict__ invmax,
        const unsigned* __restrict__ trigT,
        unsigned* __restrict__ h2, float* __restrict__ cP0) {
    __shared__ __align__(16) unsigned short LB[2 * 32 * SP];   // 32768 B exactly
    unsigned short* sh_hA = LB;
    unsigned short* sh_ph = LB + 32 * SP;
    int tid = threadIdx.x;
    int b = blockIdx.y;
    int s = blockIdx.x * 256 + tid;
    float xv = x[(size_t)b * SS + s];
    float g  = pd[s] * invmax[0];
    const uint4* trow = (const uint4*)(trigT + (size_t)s * 16);
    uint4 tc0 = trow[0], tc1 = trow[1], ts0 = trow[2], ts1 = trow[3];
    unsigned c8[8] = {tc0.x, tc0.y, tc0.z, tc0.w, tc1.x, tc1.y, tc1.z, tc1.w};
    unsigned s8[8] = {ts0.x, ts0.y, ts0.z, ts0.w, ts1.x, ts1.y, ts1.z, ts1.w};
    #pragma unroll
    for (int m = 0; m < NM; ++m) {
        unsigned cd = c8[m >> 1], sd = s8[m >> 1];
        sh_ph[swzi(m, tid)]      = (unsigned short)((m & 1) ? (cd >> 16) : (cd & 0xFFFFu));
        sh_ph[swzi(16 + m, tid)] = (unsigned short)((m & 1) ? (sd >> 16) : (sd & 0xFFFFu));
    }
    unsigned hv[CC / 2];
    #pragma unroll
    for (int p = 0; p < CC / 2; ++p) {
        int c0 = 2 * p, c1i = 2 * p + 1;
        // R24: packed affine (scalar s_loads stay scalar — R15 lesson)
        floatx2 wv = {w[c0], w[c1i]};
        floatx2 gv = {w[CC + c0], w[CC + c1i]};
        floatx2 bv = {bias[c0], bias[c1i]};
        floatx2 v = wv * xv + gv * g + bv;
        unsigned dw = cvtpk(v.x, v.y);                 // R23: HW RNE pair
        hv[p] = dw;
        sh_hA[swzi(c0, tid)]  = (unsigned short)(dw & 0xFFFFu);
        sh_hA[swzi(c1i, tid)] = (unsigned short)(dw >> 16);
    }
    unsigned* hp2 = h2 + ((size_t)b * SS + s) * HREC;
    *(uint4*)(hp2)     = (uint4){hv[0], hv[1], hv[2], hv[3]};
    *(uint4*)(hp2 + 4) = (uint4){hv[4], hv[5], hv[6], hv[7]};
    *(uint2*)(hp2 + 8) = make_uint2(hv[8], hv[9]);
    __syncthreads();
    dft_phase(sh_hA, sh_ph, tid, cP0 + ((size_t)(blockIdx.x & (NSLOT - 1)) * BB + b) * 640);
}

// ---------------- k_point_dft (layers 0..2): MFMA point-op + next-layer DFT -
// R19 structure + R20 trig table + R21 swizzle + R22 bounds + R23 cvt_pk +
// R24 gelu2 + R26 record-major h2 (wide loads, uint2-paired stores) and no
// zero-fill (garbage channels discarded by dft_phase's o<CC predicate).
__global__ __launch_bounds__(256, 4) void k_point_dft(unsigned* __restrict__ h2,
        const unsigned short* __restrict__ Bpk,
        const unsigned* __restrict__ trigT,
        float* __restrict__ cPn) {
    __shared__ __align__(16) unsigned short LB[2 * 32 * SP];   // 32768 B exactly
    unsigned short* AST   = LB;                  // 32 KB staged A-rows (all of LB)
    unsigned short* sh_hA = LB;                  // aliases, valid after barrier
    unsigned short* sh_ph = LB + 32 * SP;
    int tid = threadIdx.x;
    int b = blockIdx.y;
    int s = blockIdx.x * 256 + tid;

    // ---- phase A: table load + old-h load + A-row staging (wave-local) ----
    const uint4* trow = (const uint4*)(trigT + (size_t)s * 16);
    uint4 tc0 = trow[0], tc1 = trow[1], ts0 = trow[2], ts1 = trow[3];
    const unsigned* hp2r = h2 + ((size_t)b * SS + s) * HREC;
    uint4 h03 = *(const uint4*)(hp2r);
    uint4 h47 = *(const uint4*)(hp2r + 4);
    uint2 h89 = *(const uint2*)(hp2r + 8);
    unsigned hw[CC / 2] = {h03.x, h03.y, h03.z, h03.w, h47.x, h47.y, h47.z, h47.w, h89.x, h89.y};
    stage_A(AST, tid, hw, tc0, tc1, ts0, ts1);
    // no barrier: phase B reads only this wave's rows, written by this wave

    // ---- phase B: MFMA point-op (swapped), gelu, in-lane pack, h2 -----
    int wave = tid >> 6, lane = tid & 63, col = lane & 15, quad = lane >> 4;
    const unsigned short* Bp = Bpk + (size_t)b * 4096;
    short8 wh0[2], wh1[2], wl0[2], wl1[2];
    #pragma unroll
    for (int cht = 0; cht < 2; ++cht) {
        int o = cht * 16 + col;
        wh0[cht] = *(const short8*)(Bp + o * 64 + quad * 8);
        wh1[cht] = *(const short8*)(Bp + o * 64 + 32 + quad * 8);
        wl0[cht] = *(const short8*)(Bp + 2048 + o * 64 + quad * 8);
        wl1[cht] = *(const short8*)(Bp + 2048 + o * 64 + 32 + quad * 8);
    }
    unsigned* h2b = h2 + ((size_t)b * SS + blockIdx.x * 256) * HREC;
    unsigned pkr[2][4][2];
    #pragma unroll
    for (int st = 0; st < 4; ++st) {
        int ar = wave * 64 + st * 16 + col;
        int sw = ar & 7;
        const unsigned short* abase = AST + ar * 64;
        short8 ah0 = *(const short8*)(abase + ((quad ^ sw) << 3));
        short8 ah1 = *(const short8*)(abase + (((4 + quad) ^ sw) << 3));
        #pragma unroll
        for (int cht = 0; cht < 2; ++cht) {
            floatx4 a = {0.f, 0.f, 0.f, 0.f};
            a = __builtin_amdgcn_mfma_f32_16x16x32_bf16(wh0[cht], ah0, a, 0, 0, 0);
            a = __builtin_amdgcn_mfma_f32_16x16x32_bf16(wh1[cht], ah1, a, 0, 0, 0);
            a = __builtin_amdgcn_mfma_f32_16x16x32_bf16(wl0[cht], ah0, a, 0, 0, 0);
            a = __builtin_amdgcn_mfma_f32_16x16x32_bf16(wl1[cht], ah1, a, 0, 0, 0);
            floatx2 g01 = gelu2((floatx2){a[0], a[1]});   // R24
            floatx2 g23 = gelu2((floatx2){a[2], a[3]});
            unsigned d0 = cvtpk(g01.x, g01.y);
            unsigned d1 = cvtpk(g23.x, g23.y);
            pkr[cht][st][0] = d0;
            pkr[cht][st][1] = d1;
            int p = cht * 8 + quad * 2;               // channel pair index
            if (p < CC / 2) {                          // cht1: quad0 only
                *(uint2*)(h2b + (size_t)ar * HREC + p) = make_uint2(d0, d1);  // R26
            }
        }
    }
    __syncthreads();   // all waves' AST reads done; LDS becomes sh_hA/sh_ph

    // ---- phase C: scatter h_new to sh_hA, write sh_ph from table ------
    {
        unsigned c8[8] = {tc0.x, tc0.y, tc0.z, tc0.w, tc1.x, tc1.y, tc1.z, tc1.w};
        unsigned s8[8] = {ts0.x, ts0.y, ts0.z, ts0.w, ts1.x, ts1.y, ts1.z, ts1.w};
        #pragma unroll
        for (int m = 0; m < NM; ++m) {
            unsigned cd = c8[m >> 1], sd = s8[m >> 1];
            sh_ph[swzi(m, tid)]      = (unsigned short)((m & 1) ? (cd >> 16) : (cd & 0xFFFFu));
            sh_ph[swzi(16 + m, tid)] = (unsigned short)((m & 1) ? (sd >> 16) : (sd & 0xFFFFu));
        }
    }
    #pragma unroll
    for (int cht = 0; cht < 2; ++cht) {
        int ob = cht * 16 + quad * 4;
        if (ob < CC) {
            #pragma unroll
            for (int st = 0; st < 4; ++st) {
                int s_loc = wave * 64 + st * 16 + col;
                #pragma unroll
                for (int rp = 0; rp < 2; ++rp) {
                    unsigned d = pkr[cht][st][rp];
                    sh_hA[swzi(ob + 2 * rp, s_loc)]     = (unsigned short)(d & 0xFFFFu);
                    sh_hA[swzi(ob + 2 * rp + 1, s_loc)] = (unsigned short)(d >> 16);
                }
            }
        }
    }
    __syncthreads();
    dft_phase(sh_hA, sh_ph, tid, cPn + ((size_t)(blockIdx.x & (NSLOT - 1)) * BB + b) * 640);
}

// ---------------- k_mix: partial reduce + complex mixing + B-panel pack -----
__global__ __launch_bounds__(320) void k_mix(const float* __restrict__ cP,
                                             const float* __restrict__ wre, const float* __restrict__ wim,
                                             const float* __restrict__ ww, const float* __restrict__ wb,
                                             float* __restrict__ cA, float* __restrict__ cB,
                                             unsigned short* __restrict__ Bpk) {
    int b = blockIdx.x, tid = threadIdx.x;
    __shared__ float PQ[640];
    const float* base = cP + (size_t)b * 640;
    int i = tid >> 4, m = tid & 15;
    float sP = 0.f, sQ = 0.f;
    #pragma unroll 4
    for (int sl = 0; sl < NSLOT; ++sl) {
        sP += base[(size_t)sl * BB * 640 + tid];
        sQ += base[(size_t)sl * BB * 640 + 320 + tid];
    }
    PQ[i * 32 + m]      = sP;
    PQ[i * 32 + 16 + m] = sQ;
    __syncthreads();
    int o = i;
    float reY = 0.f, imY = 0.f;
    #pragma unroll
    for (int c = 0; c < CC; ++c) {
        float P = PQ[c * 32 + m], Q = PQ[c * 32 + 16 + m];
        float wr = wre[(size_t)(c * CC + o) * NM + m];
        float wi = wim[(size_t)(c * CC + o) * NM + m];
        reY += P * wr + Q * wi;                // X = P - iQ
        imY += P * wi - Q * wr;
    }
    const float invS = 1.0f / (float)SS;
    float a, bb;
    if (m == 0) { a = reY * invS; bb = 0.0f; } // irfft drops Im(DC)
    else        { a = 2.0f * reY * invS; bb = -2.0f * imY * invS; }
    cA[(size_t)(b * CC + o) * NM + m] = a;
    cB[(size_t)(b * CC + o) * NM + m] = bb;

    // ---- pack B panels for the MFMA point-op (per-b) ------------------
    unsigned short* Bp = Bpk + (size_t)b * 4096;
    for (int idx = tid; idx < 640; idx += 320) {       // o<20, k 0..31
        int o8 = idx >> 5, k = idx & 31;
        float v = 0.f;
        if (k < CC) v = ww[o8 * CC + k];
        else if (k == CC) v = wb[o8];
        Bp[o8 * 64 + k]        = f2bf(v);
        Bp[2048 + o8 * 64 + k] = f2bflo(v);
    }
    for (int idx = tid; idx < 768; idx += 320) {       // o 20..31: zero rows
        int o8 = 20 + (idx >> 6), k = idx & 63;
        Bp[o8 * 64 + k] = 0;
        Bp[2048 + o8 * 64 + k] = 0;
    }
    Bp[o * 64 + 32 + m]        = f2bf(a);
    Bp[o * 64 + 48 + m]        = f2bf(bb);
    Bp[2048 + o * 64 + 32 + m] = f2bflo(a);
    Bp[2048 + o * 64 + 48 + m] = f2bflo(bb);
}

// ---------------- k_point_final: MFMA layer-3 point op + fc1 + gelu + fc2 ---
// R22 geometry (128 threads, hT 16 KB); R23 cvt_pk; R26 record-major h loads.
__global__ __launch_bounds__(128, 4) void k_point_final(const unsigned* __restrict__ h2,
        const unsigned short* __restrict__ Bpk,
        const unsigned short* __restrict__ w1Tg,
        const float* __restrict__ w2, const float* __restrict__ b2,
        const unsigned* __restrict__ trigT,
        float* __restrict__ out) {
    __shared__ __align__(16) unsigned short AST[128 * 64];   // 16384 B
    unsigned short* hT = AST;            // aliased, wave-local throughout
    int tid = threadIdx.x;
    int b = blockIdx.y;
    int s = blockIdx.x * 128 + tid;

    // ---- phase A: table load + h load + A-row staging -----------------
    const uint4* trow = (const uint4*)(trigT + (size_t)s * 16);
    uint4 tc0 = trow[0], tc1 = trow[1], ts0 = trow[2], ts1 = trow[3];
    const unsigned* hp2r = h2 + ((size_t)b * SS + s) * HREC;
    uint4 h03 = *(const uint4*)(hp2r);
    uint4 h47 = *(const uint4*)(hp2r + 4);
    uint2 h89 = *(const uint2*)(hp2r + 8);
    unsigned hw[CC / 2] = {h03.x, h03.y, h03.z, h03.w, h47.x, h47.y, h47.z, h47.w, h89.x, h89.y};
    stage_A(AST, tid, hw, tc0, tc1, ts0, ts1);
    // no barrier: wave-local

    // ---- phase B: point-op MFMA (swapped, no gelu) --------------------
    int wave = tid >> 6, lane = tid & 63, col = lane & 15, quad = lane >> 4;
    const unsigned short* Bp = Bpk + (size_t)b * 4096;
    short8 wh0[2], wh1[2], wl0[2], wl1[2];
    #pragma unroll
    for (int cht = 0; cht < 2; ++cht) {
        int o = cht * 16 + col;
        wh0[cht] = *(const short8*)(Bp + o * 64 + quad * 8);
        wh1[cht] = *(const short8*)(Bp + o * 64 + 32 + quad * 8);
        wl0[cht] = *(const short8*)(Bp + 2048 + o * 64 + quad * 8);
        wl1[cht] = *(const short8*)(Bp + 2048 + o * 64 + 32 + quad * 8);
    }
    float res[2][4][4];   // [cht][st][r] — statically indexed
    #pragma unroll
    for (int st = 0; st < 4; ++st) {
        int ar = wave * 64 + st * 16 + col;
        int sw = ar & 7;
        const unsigned short* abase = AST + ar * 64;
        short8 ah0 = *(const short8*)(abase + ((quad ^ sw) << 3));
        short8 ah1 = *(const short8*)(abase + (((4 + quad) ^ sw) << 3));
        #pragma unroll
        for (int cht = 0; cht < 2; ++cht) {
            floatx4 a = {0.f, 0.f, 0.f, 0.f};
            a = __builtin_amdgcn_mfma_f32_16x16x32_bf16(wh0[cht], ah0, a, 0, 0, 0);
            a = __builtin_amdgcn_mfma_f32_16x16x32_bf16(wh1[cht], ah1, a, 0, 0, 0);
            a = __builtin_amdgcn_mfma_f32_16x16x32_bf16(wl0[cht], ah0, a, 0, 0, 0);
            a = __builtin_amdgcn_mfma_f32_16x16x32_bf16(wl1[cht], ah1, a, 0, 0, 0);
            #pragma unroll
            for (int r = 0; r < 4; ++r) res[cht][st][r] = a[r];
        }
    }
    // no barrier: phase C writes this wave's own rows only

    // ---- phase C: in-lane hi/lo cvt_pk into hT; dwi==10 = (ONE,0) slot ----
    #pragma unroll
    for (int cht = 0; cht < 2; ++cht) {
        #pragma unroll
        for (int st = 0; st < 4; ++st) {
            int row = wave * 64 + st * 16 + col;
            int sw = row & 7;
            unsigned* rb = (unsigned*)(hT + row * WP);
            #pragma unroll
            for (int rp = 0; rp < 2; ++rp) {
                int dwi = cht * 8 + quad * 2 + rp;
                if (dwi <= CC / 2) {                   // 10 = bias ONE slot
                    float f0, f1;
                    if (dwi == CC / 2) { f0 = 1.0f; f1 = 0.0f; }
                    else { f0 = res[cht][st][2 * rp]; f1 = res[cht][st][2 * rp + 1]; }
                    unsigned hd = cvtpk(f0, f1);                      // R23
                    float r0 = asf(hd << 16), r1 = asf(hd & 0xFFFF0000u);
                    unsigned ld = cvtpk(f0 - r0, f1 - r1);
                    int chunk = dwi >> 2, pos = dwi & 3;
                    rb[((chunk ^ sw) << 2) + pos]       = hd;
                    rb[(((chunk + 4) ^ sw) << 2) + pos] = ld;
                }
            }
        }
    }
    // no barrier: fc1 reads this wave's own rows only

    // ---- fc1 MFMA (bias in MFMA) + gelu + fc2 --------------------------
    short8 bhi[8], blo[8];
    #pragma unroll
    for (int nt = 0; nt < 8; ++nt) {
        bhi[nt] = *(const short8*)(w1Tg + (size_t)(nt * 16 + col) * 64 + quad * 8);
        blo[nt] = *(const short8*)(w1Tg + (size_t)(nt * 16 + col) * 64 + 32 + quad * 8);
    }
    float w2r[8];
    #pragma unroll
    for (int nt = 0; nt < 8; ++nt) w2r[nt] = w2[nt * 16 + col];
    float b2v = b2[0];
    #pragma unroll
    for (int mt = 0; mt < 4; ++mt) {
        int srow = wave * 64 + mt * 16 + col;     // A row m = lane&15
        int sw = srow & 7;
        short8 ahi = *(const short8*)(hT + srow * WP + ((quad ^ sw) << 3));
        short8 alo = *(const short8*)(hT + srow * WP + (((quad ^ sw) ^ 4) << 3));
        float part[4] = {0.f, 0.f, 0.f, 0.f};
        #pragma unroll
        for (int nt = 0; nt < 8; ++nt) {
            floatx4 a = {0.f, 0.f, 0.f, 0.f};
            a = __builtin_amdgcn_mfma_f32_16x16x32_bf16(ahi, bhi[nt], a, 0, 0, 0);
            a = __builtin_amdgcn_mfma_f32_16x16x32_bf16(ahi, blo[nt], a, 0, 0, 0);
            a = __builtin_amdgcn_mfma_f32_16x16x32_bf16(alo, bhi[nt], a, 0, 0, 0);
            #pragma unroll
            for (int r = 0; r < 4; ++r) {
                float t = gelu_fast(a[r]);
                part[r] += t * w2r[nt];
            }
        }
        #pragma unroll
        for (int r = 0; r < 4; ++r) {
            float p = row16_sum(part[r]);
            if (col == 0) {
                int row = wave * 64 + mt * 16 + quad * 4 + r;   // dead rows of this tile
                *(float*)(&hT[row * WP + ((row & 7) << 3)]) = p + b2v;
            }
        }
    }
    __syncthreads();      // the single cross-wave hand-off
    out[(size_t)b * SS + blockIdx.x * 128 + tid] = *(const float*)(&hT[tid * WP + ((tid & 7) << 3)]);
}

extern "C" void kernel_launch(void* const* d_in, const int* in_sizes, int n_in,
                              void* d_out, int out_size, void* d_ws, size_t ws_size,
                              hipStream_t stream) {
    (void)in_sizes; (void)n_in; (void)out_size; (void)ws_size;
    const float* x    = (const float*)d_in[0];
    const float* pd   = (const float*)d_in[1];
    const float* fc0w = (const float*)d_in[2];
    const float* fc0b = (const float*)d_in[3];
    const float* fc1w = (const float*)d_in[4];
    const float* fc1b = (const float*)d_in[5];
    const float* fc2w = (const float*)d_in[6];
    const float* fc2b = (const float*)d_in[7];

    char* ws = (char*)d_ws;
    unsigned* h2 = (unsigned*)ws;
    size_t off = (size_t)BB * SS * HREC * 4;                          // 100.7 MB (record-major)
    float* cP = (float*)(ws + off); off += (size_t)4 * NSLOT * BB * 640 * 4;  // 5.24 MB
    float* cA = (float*)(ws + off); off += (size_t)BB * CC * NM * 4;
    float* cB = (float*)(ws + off); off += (size_t)BB * CC * NM * 4;
    float* invmax = (float*)(ws + off); off += 256;
    unsigned short* w1Tg = (unsigned short*)(ws + off); off += (size_t)HH * 64 * 2;  // 16 KB
    unsigned short* Bpk  = (unsigned short*)(ws + off); off += (size_t)BB * 4096 * 2; // 256 KB
    unsigned* trigT = (unsigned*)(ws + off); off += (size_t)SS * 16 * 4;             // 4 MB
    const size_t CPL = (size_t)NSLOT * BB * 640;   // floats per layer-slot set

    dim3 gBS(SS / 256, BB);
    dim3 gBF(SS / 128, BB);

    k_prep<<<1538, 256, 0, stream>>>(pd, fc1w, fc1b, invmax, cP, w1Tg, trigT);
    k_fc0_dft<<<gBS, 256, 0, stream>>>(x, pd, fc0w, fc0b, invmax, trigT, h2, cP);

    for (int l = 0; l < 3; ++l) {
        const float* wre = (const float*)d_in[8 + 4 * l];
        const float* wim = (const float*)d_in[9 + 4 * l];
        const float* ww  = (const float*)d_in[10 + 4 * l];
        const float* wb  = (const float*)d_in[11 + 4 * l];
        k_mix<<<BB, 320, 0, stream>>>(cP + (size_t)l * CPL, wre, wim, ww, wb, cA, cB, Bpk);
        k_point_dft<<<gBS, 256, 0, stream>>>(h2, Bpk, trigT, cP + (size_t)(l + 1) * CPL);
    }
    {   // layer 3 fused with fc1/gelu/fc2
        const float* wre = (const float*)d_in[20];
        const float* wim = (const float*)d_in[21];
        const float* ww  = (const float*)d_in[22];
        const float* wb  = (const float*)d_in[23];
        k_mix<<<BB, 320, 0, stream>>>(cP + (size_t)3 * CPL, wre, wim, ww, wb, cA, cB, Bpk);
        k_point_final<<<gBF, 128, 0, stream>>>(h2, Bpk, w1Tg, fc2w, fc2b, trigT, (float*)d_out);
    }
}